// Round 14
// baseline (1062.761 us; speedup 1.0000x reference)
//
#include <hip/hip_runtime.h>
#include <stdint.h>

#define DEV __device__ __forceinline__

typedef unsigned short u16;
typedef __attribute__((ext_vector_type(8))) short short8;
typedef __attribute__((ext_vector_type(4))) float floatx4;

#define B_ 2
#define T_ 1024
#define C_ 768
#define H_ 12
#define L_ 6
#define V_ 32000
#define F_ 3072
#define M_ 2048   // B*T
#define C3_ 2304  // 3*C (packed qkv)

#define VMW(n) asm volatile("s_waitcnt vmcnt(" #n ")" ::: "memory")
#define LGKM0 asm volatile("s_waitcnt lgkmcnt(0)" ::: "memory")
#define SBAR __builtin_amdgcn_s_barrier()
#define SCHED0 __builtin_amdgcn_sched_barrier(0)

DEV u16 f2bf(float f) {
  unsigned int u; __builtin_memcpy(&u, &f, 4);
  u += 0x7FFFu + ((u >> 16) & 1u);   // round-to-nearest-even
  return (u16)(u >> 16);
}

// async global->LDS, 16B per lane. LDS ptr wave-uniform; HW adds lane*16.
DEV void gload16(const void* g, void* l) {
  __builtin_amdgcn_global_load_lds(
      (__attribute__((address_space(1))) void*)(uintptr_t)g,
      (__attribute__((address_space(3))) void*)(unsigned int)(uintptr_t)l,
      16, 0, 0);
}

// bijective XCD swizzle (m204)
DEV int xcd_swz(int flat, int nwg) {
  int q = nwg >> 3, r = nwg & 7;
  int xcd = flat & 7, sid = flat >> 3;
  return (xcd < r ? xcd * (q + 1) : r * (q + 1) + (xcd - r) * q) + sid;
}

// ---------------- transpose + f32->bf16 convert: src[z][R][Cc] -> dst[Cc][R] ----------------
__global__ __launch_bounds__(256) void transpose_f32_bf16(
    const float* __restrict__ src, u16* __restrict__ dst, int R, int Cc,
    size_t src_z, size_t dst_z) {
  __shared__ float tile[32][33];
  const float* s = src + (size_t)blockIdx.z * src_z;
  u16* d = dst + (size_t)blockIdx.z * dst_z;
  int c0 = blockIdx.x * 32, r0 = blockIdx.y * 32;
  int tx = threadIdx.x & 31, ty = threadIdx.x >> 5;
#pragma unroll
  for (int i = 0; i < 4; i++)
    tile[ty + 8 * i][tx] = s[(size_t)(r0 + ty + 8 * i) * Cc + (c0 + tx)];
  __syncthreads();
#pragma unroll
  for (int i = 0; i < 4; i++)
    d[(size_t)(c0 + ty + 8 * i) * R + (r0 + tx)] = f2bf(tile[tx][ty + 8 * i]);
}

// ---------------- batched CxC transpose for wq/wk/wv/wo (z = l*4 + wsel) ----------------
__global__ __launch_bounds__(256) void transpose4_qkvo(
    const float* __restrict__ wq, const float* __restrict__ wk,
    const float* __restrict__ wv, const float* __restrict__ wo,
    u16* __restrict__ wqkvT, u16* __restrict__ woT) {
  __shared__ float tile[32][33];
  int z = blockIdx.z;
  int l = z >> 2, wsel = z & 3;
  size_t CC = (size_t)C_ * C_;
  const float* s = (wsel == 0 ? wq : wsel == 1 ? wk : wsel == 2 ? wv : wo) + (size_t)l * CC;
  u16* d = (wsel < 3) ? (wqkvT + (size_t)l * 3 * CC + (size_t)wsel * CC)
                      : (woT + (size_t)l * CC);
  int c0 = blockIdx.x * 32, r0 = blockIdx.y * 32;
  int tx = threadIdx.x & 31, ty = threadIdx.x >> 5;
#pragma unroll
  for (int i = 0; i < 4; i++)
    tile[ty + 8 * i][tx] = s[(size_t)(r0 + ty + 8 * i) * C_ + (c0 + tx)];
  __syncthreads();
#pragma unroll
  for (int i = 0; i < 4; i++)
    d[(size_t)(c0 + ty + 8 * i) * C_ + (r0 + tx)] = f2bf(tile[tx][ty + 8 * i]);
}

// ---------------- fused embedding + layer-0 LN1: writes x (f32) and hb (bf16) ----------------
__global__ __launch_bounds__(256) void embed_ln(
    const int* __restrict__ idx, const float* __restrict__ tok,
    const float* __restrict__ pos, const float* __restrict__ g,
    const float* __restrict__ b, float* __restrict__ x, u16* __restrict__ out) {
  int row = blockIdx.x;
  int t = row & (T_ - 1);
  int tk = idx[row];
  const float* tp = tok + (size_t)tk * C_;
  const float* pp = pos + (size_t)t * C_;
  float* xp = x + (size_t)row * C_;
  int tid = threadIdx.x;
  float v0 = tp[tid] + pp[tid];
  float v1 = tp[tid + 256] + pp[tid + 256];
  float v2 = tp[tid + 512] + pp[tid + 512];
  xp[tid] = v0; xp[tid + 256] = v1; xp[tid + 512] = v2;
  float s = v0 + v1 + v2;
  float ss = v0 * v0 + v1 * v1 + v2 * v2;
#pragma unroll
  for (int o = 32; o > 0; o >>= 1) { s += __shfl_down(s, o); ss += __shfl_down(ss, o); }
  __shared__ float red[8];
  int wid = tid >> 6;
  if ((tid & 63) == 0) { red[wid] = s; red[4 + wid] = ss; }
  __syncthreads();
  float tot = red[0] + red[1] + red[2] + red[3];
  float tss = red[4] + red[5] + red[6] + red[7];
  float mean = tot * (1.f / C_);
  float var = tss * (1.f / C_) - mean * mean;
  float rstd = rsqrtf(var + 1e-5f);
  u16* op = out + (size_t)row * C_;
  op[tid]       = f2bf((v0 - mean) * rstd * g[tid]       + b[tid]);
  op[tid + 256] = f2bf((v1 - mean) * rstd * g[tid + 256] + b[tid + 256]);
  op[tid + 512] = f2bf((v2 - mean) * rstd * g[tid + 512] + b[tid + 512]);
}

// ---------------- layernorm: f32 in -> bf16 out ----------------
__global__ __launch_bounds__(256) void ln_kernel(
    const float* __restrict__ x, const float* __restrict__ g,
    const float* __restrict__ b, u16* __restrict__ out) {
  int row = blockIdx.x;
  int tid = threadIdx.x;
  const float* xp = x + (size_t)row * C_;
  float v0 = xp[tid], v1 = xp[tid + 256], v2 = xp[tid + 512];
  float s = v0 + v1 + v2;
  float ss = v0 * v0 + v1 * v1 + v2 * v2;
#pragma unroll
  for (int o = 32; o > 0; o >>= 1) { s += __shfl_down(s, o); ss += __shfl_down(ss, o); }
  __shared__ float red[8];
  int wid = tid >> 6;
  if ((tid & 63) == 0) { red[wid] = s; red[4 + wid] = ss; }
  __syncthreads();
  float tot = red[0] + red[1] + red[2] + red[3];
  float tss = red[4] + red[5] + red[6] + red[7];
  float mean = tot * (1.f / C_);
  float var = tss * (1.f / C_) - mean * mean;
  float rstd = rsqrtf(var + 1e-5f);
  u16* op = out + (size_t)row * C_;
  op[tid]       = f2bf((v0 - mean) * rstd * g[tid]       + b[tid]);
  op[tid + 256] = f2bf((v1 - mean) * rstd * g[tid + 256] + b[tid + 256]);
  op[tid + 512] = f2bf((v2 - mean) * rstd * g[tid + 512] + b[tid + 512]);
}

// ---------------- GEMM (layer ops): BK=32, 3-deep ring + counted vmcnt (R5-proven) ----------------
template <int THREADS, int BM, int BN, int WM, int WN, int BIAS, int RELU, int OUTMODE, int SPLITK>
__global__ __launch_bounds__(THREADS) void gemm3(
    const u16* __restrict__ A, const u16* __restrict__ BT,
    const float* __restrict__ bias,
    u16* __restrict__ ob, float* __restrict__ fout, u16* __restrict__ vt,
    int N, int K) {
  constexpr int ALOADS = (BM * 64) / (THREADS * 16);
  constexpr int BLOADS = (BN * 64) / (THREADS * 16);
  constexpr int LDS_L = ALOADS + BLOADS;
  constexpr int MF = BM / (WM * 16);
  constexpr int NF = BN / (WN * 16);
  __shared__ __align__(16) u16 As[3][BM * 32];
  __shared__ __align__(16) u16 Bs[3][BN * 32];

  int tid = threadIdx.x;
  int lane = tid & 63, w = tid >> 6;
  int wm = w / WN, wn = w % WN;
  int rr = lane & 15, qg = lane >> 4;

  int gx = gridDim.x;
  int nwg = gx * gridDim.y;
  int flat = blockIdx.y * gx + blockIdx.x;
  int wg = xcd_swz(flat, nwg);
  int m0 = (wg % gx) * BM, n0 = (wg / gx) * BN;

  int kz = SPLITK > 1 ? blockIdx.z : 0;
  int Keff = SPLITK > 1 ? (K / SPLITK) : K;
  int kbase = kz * Keff;

  const u16* Aps[ALOADS];
  const u16* Bps[BLOADS];
#pragma unroll
  for (int i = 0; i < ALOADS; i++) {
    int idx = i * THREADS + tid;
    int row = idx >> 2;
    int chunk = (idx & 3) ^ ((row >> 1) & 3);
    Aps[i] = A + (size_t)(m0 + row) * K + chunk * 8 + kbase;
  }
#pragma unroll
  for (int i = 0; i < BLOADS; i++) {
    int idx = i * THREADS + tid;
    int row = idx >> 2;
    int chunk = (idx & 3) ^ ((row >> 1) & 3);
    Bps[i] = BT + (size_t)(n0 + row) * K + chunk * 8 + kbase;
  }

  auto stage = [&](int sl, int kk) {
#pragma unroll
    for (int i = 0; i < ALOADS; i++)
      gload16(Aps[i] + kk, (char*)As + (size_t)sl * BM * 64 + i * THREADS * 16 + w * 1024);
#pragma unroll
    for (int i = 0; i < BLOADS; i++)
      gload16(Bps[i] + kk, (char*)Bs + (size_t)sl * BN * 64 + i * THREADS * 16 + w * 1024);
  };

  floatx4 zero = {0.f, 0.f, 0.f, 0.f};
  floatx4 acc[MF][NF];
#pragma unroll
  for (int i = 0; i < MF; i++)
#pragma unroll
    for (int j = 0; j < NF; j++) acc[i][j] = zero;

  int NT = Keff >> 5;
  stage(0, 0);
  stage(1, 32);
  if constexpr (LDS_L == 2) VMW(2);
  else if constexpr (LDS_L == 3) VMW(3);
  else if constexpr (LDS_L == 4) VMW(4);
  else VMW(6);
  SBAR;
  SCHED0;

  int sqA = (qg ^ ((rr >> 1) & 3)) << 4;

  for (int t = 0; t < NT; ++t) {
    int sl = t % 3;
    if (t + 2 < NT) stage((t + 2) % 3, (t + 2) << 5);
    SCHED0;
    const char* Ab = (const char*)As + (size_t)sl * BM * 64;
    const char* Bb = (const char*)Bs + (size_t)sl * BN * 64;
    short8 af[MF], bf[NF];
#pragma unroll
    for (int i = 0; i < MF; i++)
      af[i] = *(const short8*)(Ab + ((wm * (BM / WM) + i * 16 + rr) << 6) + sqA);
#pragma unroll
    for (int j = 0; j < NF; j++)
      bf[j] = *(const short8*)(Bb + ((wn * (BN / WN) + j * 16 + rr) << 6) + sqA);
    __builtin_amdgcn_s_setprio(1);
#pragma unroll
    for (int i = 0; i < MF; i++)
#pragma unroll
      for (int j = 0; j < NF; j++)
        acc[i][j] = __builtin_amdgcn_mfma_f32_16x16x32_bf16(af[i], bf[j], acc[i][j], 0, 0, 0);
    __builtin_amdgcn_s_setprio(0);
    if (t < NT - 2) {
      if constexpr (LDS_L == 2) VMW(2);
      else if constexpr (LDS_L == 3) VMW(3);
      else if constexpr (LDS_L == 4) VMW(4);
      else VMW(6);
    } else if (t == NT - 2) VMW(0);
    if (t < NT - 1) { SBAR; SCHED0; }
  }

  int cb = n0 + wn * (BN / WN);
  int rb = m0 + wm * (BM / WM);
  bool isv = (OUTMODE == 3) && (n0 >= 1536);
#pragma unroll
  for (int i = 0; i < MF; i++) {
#pragma unroll
    for (int j = 0; j < NF; j++) {
      int col = cb + j * 16 + rr;
      float bv = 0.f;
      if (BIAS && kz == 0) bv = bias[col];
      float vals[4];
#pragma unroll
      for (int r = 0; r < 4; r++) {
        float val = acc[i][j][r] + bv;
        if (RELU) val = fmaxf(val, 0.f);
        vals[r] = val;
      }
      int row0 = rb + i * 16 + qg * 4;
      if (isv) {
        int colv = col - 1536;
        int bb = row0 >> 10, t0 = row0 & (T_ - 1);
        uint2 pk;
        pk.x = (unsigned int)f2bf(vals[0]) | ((unsigned int)f2bf(vals[1]) << 16);
        pk.y = (unsigned int)f2bf(vals[2]) | ((unsigned int)f2bf(vals[3]) << 16);
        *(uint2*)&vt[((size_t)bb * C_ + colv) * T_ + t0] = pk;
      } else {
#pragma unroll
        for (int r = 0; r < 4; r++) {
          size_t o = (size_t)(row0 + r) * N + col;
          if (OUTMODE == 0 || OUTMODE == 3) ob[o] = f2bf(vals[r]);
          else if (OUTMODE == 1) {
            if (SPLITK > 1) atomicAdd(&fout[o], vals[r]);
            else fout[o] += vals[r];
          } else fout[o] = vals[r];
        }
      }
    }
  }
}

// ---------------- 256x256 logits GEMM: m201-style 8-phase; LDS-transposed dwordx4 epilogue ----
__global__ __launch_bounds__(512) void gemm8(
    const u16* __restrict__ A, const u16* __restrict__ BT,
    const float* __restrict__ bias, float* __restrict__ fout, int N, int K) {
  __shared__ __align__(16) u16 As[2][2][128 * 64];
  __shared__ __align__(16) u16 Bs[2][2][128 * 64];
  int tid = threadIdx.x;
  int lane = tid & 63, w = tid >> 6;
  int wr = w >> 2, wc = w & 3;
  int rr = lane & 15, qg = lane >> 4;

  int gx = gridDim.x;
  int nwg = gx * gridDim.y;
  int flat = blockIdx.y * gx + blockIdx.x;
  int wg = xcd_swz(flat, nwg);
  int m0 = (wg % gx) * 256, n0 = (wg / gx) * 256;

  int la = tid >> 3;
  int sa = (((tid & 7) ^ (la & 7)) << 3);
  const u16* Ap0 = A + (size_t)(m0 + la) * K + sa;
  const u16* Ap1 = A + (size_t)(m0 + 128 + la) * K + sa;
  int lb0 = la, lb1 = 64 + la;
  const u16* Bp0 = BT + (size_t)(n0 + (lb0 >> 5) * 64 + (lb0 & 31)) * K + sa;
  const u16* Bp1 = BT + (size_t)(n0 + (lb1 >> 5) * 64 + (lb1 & 31)) * K + sa;

  auto stA = [&](int buf, int mh, int kt) {
    size_t off = (size_t)mh * 64 * K + kt * 64;
    gload16(Ap0 + off, (char*)&As[buf][mh][0] + w * 1024);
    gload16(Ap1 + off, (char*)&As[buf][mh][0] + 8192 + w * 1024);
  };
  auto stB = [&](int buf, int nh, int kt) {
    size_t off = (size_t)nh * 32 * K + kt * 64;
    gload16(Bp0 + off, (char*)&Bs[buf][nh][0] + w * 1024);
    gload16(Bp1 + off, (char*)&Bs[buf][nh][0] + 8192 + w * 1024);
  };
  auto stageOrd = [&](int buf, int h, int kt) {
    if (h == 0) stA(buf, 0, kt);
    else if (h == 1) stB(buf, 0, kt);
    else if (h == 2) stB(buf, 1, kt);
    else stA(buf, 1, kt);
  };

  floatx4 zero = {0.f, 0.f, 0.f, 0.f};
  floatx4 acc[8][4];
#pragma unroll
  for (int i = 0; i < 8; i++)
#pragma unroll
    for (int j = 0; j < 4; j++) acc[i][j] = zero;

  short8 a[2][4], b[2][2];
  int NKT = K >> 6;
  int NIT = NKT >> 1;

  stageOrd(0, 0, 0); stageOrd(0, 1, 0); stageOrd(0, 2, 0); stageOrd(0, 3, 0);
  VMW(4);
  SBAR;
  SCHED0;

  for (int it = 0; it < NIT; ++it) {
    int kt2 = it * 2;
    bool last = (it == NIT - 1);
#pragma unroll
    for (int p = 0; p < 8; ++p) {
      const int d = p >> 2;
      const int q = p & 3;
      const int mh = q >> 1, nh = q & 1;
      const char* Abp = (const char*)&As[d][mh][0];
      const char* Bbp = (const char*)&Bs[d][nh][0];
      if (q == 0 || q == 2) {
#pragma unroll
        for (int kk = 0; kk < 2; kk++)
#pragma unroll
          for (int i = 0; i < 4; i++) {
            int l = wr * 64 + i * 16 + rr;
            a[kk][i] = *(const short8*)(Abp + l * 128 + ((((kk << 2) + qg) ^ (rr & 7)) << 4));
          }
      }
#pragma unroll
      for (int kk = 0; kk < 2; kk++)
#pragma unroll
        for (int j = 0; j < 2; j++) {
          int l = wc * 32 + j * 16 + rr;
          b[kk][j] = *(const short8*)(Bbp + l * 128 + ((((kk << 2) + qg) ^ (rr & 7)) << 4));
        }
      if (p < 4) stageOrd(1, q, kt2 + 1);
      else if (!last) stageOrd(0, q, kt2 + 2);
      SCHED0;
      SBAR;
      LGKM0;
      SCHED0;
      __builtin_amdgcn_s_setprio(1);
#pragma unroll
      for (int kk = 0; kk < 2; kk++)
#pragma unroll
        for (int i = 0; i < 4; i++)
#pragma unroll
          for (int j = 0; j < 2; j++)
            acc[mh * 4 + i][nh * 2 + j] = __builtin_amdgcn_mfma_f32_16x16x32_bf16(
                a[kk][i], b[kk][j], acc[mh * 4 + i][nh * 2 + j], 0, 0, 0);
      __builtin_amdgcn_s_setprio(0);
      if (!last || p < 4) VMW(4);
      else if (p == 4) VMW(2);
      else if (p == 5) VMW(0);
      SBAR;
      SCHED0;
    }
  }

  // epilogue: per-wave LDS transpose (reuse As; 16x68-f32 slot, 2-way-max banks) -> dwordx4 stores
  float* eps = (float*)((char*)&As[0][0][0] + (size_t)w * (16 * 68 * 4));
  int erow = lane >> 2, ec0 = (lane & 3) << 4;
  int rbase = m0 + wr * 128;
  int cbase = n0 + wc * 64;
#pragma unroll
  for (int fi = 0; fi < 8; fi++) {
    int rowc = rbase + (fi >> 2) * 64 + (fi & 3) * 16;
#pragma unroll
    for (int fj = 0; fj < 4; fj++) {
      int lc = (fj >> 1) * 32 + (fj & 1) * 16 + rr;
      float bv = bias[cbase + lc];
#pragma unroll
      for (int r = 0; r < 4; r++)
        eps[(qg * 4 + r) * 68 + lc] = acc[fi][fj][r] + bv;
    }
#pragma unroll
    for (int k = 0; k < 4; k++) {
      floatx4 v = *(const floatx4*)&eps[erow * 68 + ec0 + 4 * k];
      *(floatx4*)&fout[(size_t)(rowc + erow) * N + (cbase + ec0 + 4 * k)] = v;
    }
  }
}

// ---------------- fused causal attention: 4-wave KV-split + online-softmax merge ----------------
__global__ __launch_bounds__(256) void attn_kernel(
    const u16* __restrict__ qkv, const u16* __restrict__ vt, u16* __restrict__ o) {
  __shared__ __align__(16) u16 P_s[4][16 * 48];
  __shared__ float mls[3][2][16];
  __shared__ float osm[3][16][64];
  int nwg = gridDim.x;
  int wg = xcd_swz(blockIdx.x, nwg);
  int qt = wg & 63;
  int h = (wg >> 6) % H_;
  int b = wg / (64 * H_);
  int q0 = qt << 4;
  int tid = threadIdx.x;
  int ws = tid >> 6;
  int lane = tid & 63;
  int rr = lane & 15, qg = lane >> 4, kq = qg << 3;

  const u16* qb = qkv + (size_t)(b * T_ + q0 + rr) * C3_ + h * 64;
  short8 qf0 = *(const short8*)(qb + kq);
  short8 qf1 = *(const short8*)(qb + 32 + kq);

  float m_r = -1e30f, l_r = 0.f;
  floatx4 zero = {0.f, 0.f, 0.f, 0.f};
  floatx4 oacc[4];
#pragma unroll
  for (int d = 0; d < 4; d++) oacc[d] = zero;

  const u16* kbase = qkv + (size_t)(b * T_) * C3_ + 768 + h * 64;
  const u16* vbase = vt + (size_t)(b * C_ + h * 64) * T_;

  for (int kt0 = ws * 32; kt0 <= q0 + 15; kt0 += 128) {
    floatx4 s[2];
#pragma unroll
    for (int c = 0; c < 2; c++) {
      const u16* kb = kbase + (size_t)(kt0 + c * 16 + rr) * C3_;
      short8 kf0 = *(const short8*)(kb + kq);
      short8 kf1 = *(const short8*)(kb + 32 + kq);
      floatx4 z = zero;
      z = __builtin_amdgcn_mfma_f32_16x16x32_bf16(kf0, qf0, z, 0, 0, 0);
      z = __builtin_amdgcn_mfma_f32_16x16x32_bf16(kf1, qf1, z, 0, 0, 0);
      s[c] = z;
    }
    int qpos = q0 + rr;
    float p[2][4];
    float mx = -1e30f;
#pragma unroll
    for (int c = 0; c < 2; c++)
#pragma unroll
      for (int r = 0; r < 4; r++) {
        int kpos = kt0 + c * 16 + qg * 4 + r;
        float val = s[c][r] * 0.125f;
        val = (kpos <= qpos) ? val : -1e30f;
        p[c][r] = val;
        mx = fmaxf(mx, val);
      }
    mx = fmaxf(mx, __shfl_xor(mx, 16));
    mx = fmaxf(mx, __shfl_xor(mx, 32));
    float mn = fmaxf(m_r, mx);
    float escL = exp2f((m_r - mn) * 1.44269504f);
    m_r = mn;
    float ps = 0.f;
#pragma unroll
    for (int c = 0; c < 2; c++)
#pragma unroll
      for (int r = 0; r < 4; r++) {
        float pv = exp2f((p[c][r] - mn) * 1.44269504f);
        p[c][r] = pv;
        ps += pv;
      }
    ps += __shfl_xor(ps, 16);
    ps += __shfl_xor(ps, 32);
    l_r = l_r * escL + ps;
#pragma unroll
    for (int c = 0; c < 2; c++) {
      unsigned int u0 = (unsigned int)f2bf(p[c][0]) | ((unsigned int)f2bf(p[c][1]) << 16);
      unsigned int u1 = (unsigned int)f2bf(p[c][2]) | ((unsigned int)f2bf(p[c][3]) << 16);
      uint2 pk; pk.x = u0; pk.y = u1;
      *(uint2*)&P_s[ws][rr * 48 + c * 16 + qg * 4] = pk;
    }
    float er[4];
#pragma unroll
    for (int r = 0; r < 4; r++) er[r] = __shfl(escL, qg * 4 + r);
#pragma unroll
    for (int d = 0; d < 4; d++)
#pragma unroll
      for (int r = 0; r < 4; r++) oacc[d][r] *= er[r];
    short8 pa = *(const short8*)&P_s[ws][rr * 48 + kq];
#pragma unroll
    for (int d = 0; d < 4; d++) {
      short8 vf = *(const short8*)(vbase + (size_t)(d * 16 + rr) * T_ + kt0 + kq);
      oacc[d] = __builtin_amdgcn_mfma_f32_16x16x32_bf16(pa, vf, oacc[d], 0, 0, 0);
    }
  }

  // partials -> LDS (waves 1..3); merge in wave 0
  if (ws != 0) {
    if (qg == 0) { mls[ws - 1][0][rr] = m_r; mls[ws - 1][1][rr] = l_r; }
#pragma unroll
    for (int d = 0; d < 4; d++)
#pragma unroll
      for (int r = 0; r < 4; r++)
        osm[ws - 1][qg * 4 + r][d * 16 + rr] = oacc[d][r];
  }
  __syncthreads();
  if (ws == 0) {
#pragma unroll
    for (int s2 = 0; s2 < 3; s2++) {
      float mw = mls[s2][0][rr];
      float lw = mls[s2][1][rr];
      float mn = fmaxf(m_r, mw);
      float e0 = exp2f((m_r - mn) * 1.44269504f);
      float e1 = exp2f((mw - mn) * 1.44269504f);
      m_r = mn;
      l_r = l_r * e0 + lw * e1;
      float er0[4], er1[4];
#pragma unroll
      for (int r = 0; r < 4; r++) {
        er0[r] = __shfl(e0, qg * 4 + r);
        er1[r] = __shfl(e1, qg * 4 + r);
      }
#pragma unroll
      for (int d = 0; d < 4; d++)
#pragma unroll
        for (int r = 0; r < 4; r++)
          oacc[d][r] = oacc[d][r] * er0[r] + osm[s2][qg * 4 + r][d * 16 + rr] * er1[r];
    }
    float lb[4];
#pragma unroll
    for (int r = 0; r < 4; r++) lb[r] = __shfl(l_r, qg * 4 + r);
    u16* obp = o + (size_t)(b * T_ + q0) * C_ + h * 64;
#pragma unroll
    for (int d = 0; d < 4; d++)
#pragma unroll
      for (int r = 0; r < 4; r++) {
        int row = qg * 4 + r;
        obp[(size_t)row * C_ + d * 16 + rr] = f2bf(oacc[d][r] / lb[r]);
      }
  }
}

extern "C" void kernel_launch(void* const* d_in, const int* in_sizes, int n_in,
                              void* d_out, int out_size, void* d_ws, size_t ws_size,
                              hipStream_t stream) {
  (void)in_sizes; (void)n_in; (void)out_size; (void)ws_size;
  const int*   xidx = (const int*)d_in[0];
  const float* tok  = (const float*)d_in[1];
  const float* pos  = (const float*)d_in[2];
  const float* ln1g = (const float*)d_in[3];
  const float* ln1b = (const float*)d_in[4];
  const float* wq   = (const float*)d_in[5];
  const float* wk   = (const float*)d_in[6];
  const float* wv   = (const float*)d_in[7];
  const float* wo   = (const float*)d_in[8];
  const float* bo   = (const float*)d_in[9];
  const float* ln2g = (const float*)d_in[10];
  const float* ln2b = (const float*)d_in[11];
  const float* w1   = (const float*)d_in[12];
  const float* b1   = (const float*)d_in[13];
  const float* w2   = (const float*)d_in[14];
  const float* b2   = (const float*)d_in[15];
  const float* lnfg = (const float*)d_in[16];
  const float* lnfb = (const float*)d_in[17];
  const float* wp   = (const float*)d_in[18];
  const float* bp   = (const float*)d_in[19];

  char* ws = (char*)d_ws;
  size_t off = 0;
  auto alloc = [&](size_t bytes) { char* p = ws + off; off += (bytes + 255) & ~(size_t)255; return p; };
  u16* wqkvT = (u16*)alloc((size_t)L_ * 3 * C_ * C_ * 2);   // [l][3C][C]
  u16* woT = (u16*)alloc((size_t)L_ * C_ * C_ * 2);
  u16* w1T = (u16*)alloc((size_t)L_ * C_ * F_ * 2);
  u16* w2T = (u16*)alloc((size_t)L_ * C_ * F_ * 2);
  u16* wpT = (u16*)alloc((size_t)C_ * V_ * 2);
  float* x = (float*)alloc((size_t)M_ * C_ * 4);
  u16* hb   = (u16*)alloc((size_t)M_ * C_ * 2);
  u16* qkvb = (u16*)alloc((size_t)M_ * C3_ * 2);
  u16* vtb  = (u16*)alloc((size_t)M_ * C_ * 2);
  u16* aob  = (u16*)alloc((size_t)M_ * C_ * 2);
  u16* mb   = (u16*)alloc((size_t)M_ * F_ * 2);

  dim3 blk(256);
  size_t CC = (size_t)C_ * C_, CF = (size_t)C_ * F_;
  transpose4_qkvo<<<dim3(C_ / 32, C_ / 32, L_ * 4), blk, 0, stream>>>(
      wq, wk, wv, wo, wqkvT, woT);
  transpose_f32_bf16<<<dim3(F_ / 32, C_ / 32, L_), blk, 0, stream>>>(w1, w1T, C_, F_, CF, CF);
  transpose_f32_bf16<<<dim3(C_ / 32, F_ / 32, L_), blk, 0, stream>>>(w2, w2T, F_, C_, CF, CF);
  transpose_f32_bf16<<<dim3(V_ / 32, C_ / 32, 1), blk, 0, stream>>>(wp, wpT, C_, V_, 0, 0);
  embed_ln<<<M_, blk, 0, stream>>>(xidx, tok, pos, ln1g, ln1b, x, hb);

  for (int l = 0; l < L_; ++l) {
    size_t wOff = (size_t)l * 3 * CC;
    size_t oOff = (size_t)l * CC;
    size_t fOff = (size_t)l * CF;
    if (l > 0)
      ln_kernel<<<M_, blk, 0, stream>>>(x, ln1g + l * C_, ln1b + l * C_, hb);
    gemm3<256, 128, 128, 2, 2, 0, 0, 3, 1><<<dim3(M_ / 128, C3_ / 128), 256, 0, stream>>>(
        hb, wqkvT + wOff, nullptr, qkvb, nullptr, vtb, C3_, C_);
    attn_kernel<<<B_ * H_ * (T_ / 16), dim3(256), 0, stream>>>(qkvb, vtb, aob);
    gemm3<256, 128, 128, 2, 2, 1, 0, 1, 2><<<dim3(M_ / 128, C_ / 128, 2), 256, 0, stream>>>(
        aob, woT + oOff, bo + l * C_, nullptr, x, nullptr, C_, C_);
    ln_kernel<<<M_, blk, 0, stream>>>(x, ln2g + l * C_, ln2b + l * C_, hb);
    gemm3<256, 128, 128, 2, 2, 1, 1, 0, 1><<<dim3(M_ / 128, F_ / 128), 256, 0, stream>>>(
        hb, w1T + fOff, b1 + l * F_, mb, nullptr, nullptr, F_, C_);
    gemm3<256, 128, 128, 2, 2, 1, 0, 1, 2><<<dim3(M_ / 128, C_ / 128, 2), 256, 0, stream>>>(
        mb, w2T + fOff, b2 + l * C_, nullptr, x, nullptr, C_, F_);
  }
  ln_kernel<<<M_, blk, 0, stream>>>(x, lnfg, lnfb, hb);
  gemm8<<<dim3(M_ / 256, V_ / 256), 512, 0, stream>>>(
      hb, wpT, bp, (float*)d_out, V_, C_);
}

// Round 15
// 1025.609 us; speedup vs baseline: 1.0362x; 1.0362x over previous
//
#include <hip/hip_runtime.h>
#include <stdint.h>

#define DEV __device__ __forceinline__

typedef unsigned short u16;
typedef __attribute__((ext_vector_type(8))) short short8;
typedef __attribute__((ext_vector_type(4))) float floatx4;

#define B_ 2
#define T_ 1024
#define C_ 768
#define H_ 12
#define L_ 6
#define V_ 32000
#define F_ 3072
#define M_ 2048   // B*T
#define C3_ 2304  // 3*C (packed qkv)

#define VMW(n) asm volatile("s_waitcnt vmcnt(" #n ")" ::: "memory")
#define LGKM0 asm volatile("s_waitcnt lgkmcnt(0)" ::: "memory")
#define SBAR __builtin_amdgcn_s_barrier()
#define SCHED0 __builtin_amdgcn_sched_barrier(0)

DEV u16 f2bf(float f) {
  unsigned int u; __builtin_memcpy(&u, &f, 4);
  u += 0x7FFFu + ((u >> 16) & 1u);   // round-to-nearest-even
  return (u16)(u >> 16);
}

// async global->LDS, 16B per lane. LDS ptr wave-uniform; HW adds lane*16.
DEV void gload16(const void* g, void* l) {
  __builtin_amdgcn_global_load_lds(
      (__attribute__((address_space(1))) void*)(uintptr_t)g,
      (__attribute__((address_space(3))) void*)(unsigned int)(uintptr_t)l,
      16, 0, 0);
}

// bijective XCD swizzle (m204)
DEV int xcd_swz(int flat, int nwg) {
  int q = nwg >> 3, r = nwg & 7;
  int xcd = flat & 7, sid = flat >> 3;
  return (xcd < r ? xcd * (q + 1) : r * (q + 1) + (xcd - r) * q) + sid;
}

// ---------------- transpose + f32->bf16 convert: src[z][R][Cc] -> dst[Cc][R] ----------------
__global__ __launch_bounds__(256) void transpose_f32_bf16(
    const float* __restrict__ src, u16* __restrict__ dst, int R, int Cc,
    size_t src_z, size_t dst_z) {
  __shared__ float tile[32][33];
  const float* s = src + (size_t)blockIdx.z * src_z;
  u16* d = dst + (size_t)blockIdx.z * dst_z;
  int c0 = blockIdx.x * 32, r0 = blockIdx.y * 32;
  int tx = threadIdx.x & 31, ty = threadIdx.x >> 5;
#pragma unroll
  for (int i = 0; i < 4; i++)
    tile[ty + 8 * i][tx] = s[(size_t)(r0 + ty + 8 * i) * Cc + (c0 + tx)];
  __syncthreads();
#pragma unroll
  for (int i = 0; i < 4; i++)
    d[(size_t)(c0 + ty + 8 * i) * R + (r0 + tx)] = f2bf(tile[tx][ty + 8 * i]);
}

// ---------------- batched CxC transpose for wq/wk/wv/wo (z = l*4 + wsel) ----------------
__global__ __launch_bounds__(256) void transpose4_qkvo(
    const float* __restrict__ wq, const float* __restrict__ wk,
    const float* __restrict__ wv, const float* __restrict__ wo,
    u16* __restrict__ wqkvT, u16* __restrict__ woT) {
  __shared__ float tile[32][33];
  int z = blockIdx.z;
  int l = z >> 2, wsel = z & 3;
  size_t CC = (size_t)C_ * C_;
  const float* s = (wsel == 0 ? wq : wsel == 1 ? wk : wsel == 2 ? wv : wo) + (size_t)l * CC;
  u16* d = (wsel < 3) ? (wqkvT + (size_t)l * 3 * CC + (size_t)wsel * CC)
                      : (woT + (size_t)l * CC);
  int c0 = blockIdx.x * 32, r0 = blockIdx.y * 32;
  int tx = threadIdx.x & 31, ty = threadIdx.x >> 5;
#pragma unroll
  for (int i = 0; i < 4; i++)
    tile[ty + 8 * i][tx] = s[(size_t)(r0 + ty + 8 * i) * C_ + (c0 + tx)];
  __syncthreads();
#pragma unroll
  for (int i = 0; i < 4; i++)
    d[(size_t)(c0 + ty + 8 * i) * C_ + (r0 + tx)] = f2bf(tile[tx][ty + 8 * i]);
}

// ---------------- fused embedding + layer-0 LN1: writes x (f32) and hb (bf16) ----------------
__global__ __launch_bounds__(256) void embed_ln(
    const int* __restrict__ idx, const float* __restrict__ tok,
    const float* __restrict__ pos, const float* __restrict__ g,
    const float* __restrict__ b, float* __restrict__ x, u16* __restrict__ out) {
  int row = blockIdx.x;
  int t = row & (T_ - 1);
  int tk = idx[row];
  const float* tp = tok + (size_t)tk * C_;
  const float* pp = pos + (size_t)t * C_;
  float* xp = x + (size_t)row * C_;
  int tid = threadIdx.x;
  float v0 = tp[tid] + pp[tid];
  float v1 = tp[tid + 256] + pp[tid + 256];
  float v2 = tp[tid + 512] + pp[tid + 512];
  xp[tid] = v0; xp[tid + 256] = v1; xp[tid + 512] = v2;
  float s = v0 + v1 + v2;
  float ss = v0 * v0 + v1 * v1 + v2 * v2;
#pragma unroll
  for (int o = 32; o > 0; o >>= 1) { s += __shfl_down(s, o); ss += __shfl_down(ss, o); }
  __shared__ float red[8];
  int wid = tid >> 6;
  if ((tid & 63) == 0) { red[wid] = s; red[4 + wid] = ss; }
  __syncthreads();
  float tot = red[0] + red[1] + red[2] + red[3];
  float tss = red[4] + red[5] + red[6] + red[7];
  float mean = tot * (1.f / C_);
  float var = tss * (1.f / C_) - mean * mean;
  float rstd = rsqrtf(var + 1e-5f);
  u16* op = out + (size_t)row * C_;
  op[tid]       = f2bf((v0 - mean) * rstd * g[tid]       + b[tid]);
  op[tid + 256] = f2bf((v1 - mean) * rstd * g[tid + 256] + b[tid + 256]);
  op[tid + 512] = f2bf((v2 - mean) * rstd * g[tid + 512] + b[tid + 512]);
}

// ---------------- layernorm: f32 in -> bf16 out ----------------
__global__ __launch_bounds__(256) void ln_kernel(
    const float* __restrict__ x, const float* __restrict__ g,
    const float* __restrict__ b, u16* __restrict__ out) {
  int row = blockIdx.x;
  int tid = threadIdx.x;
  const float* xp = x + (size_t)row * C_;
  float v0 = xp[tid], v1 = xp[tid + 256], v2 = xp[tid + 512];
  float s = v0 + v1 + v2;
  float ss = v0 * v0 + v1 * v1 + v2 * v2;
#pragma unroll
  for (int o = 32; o > 0; o >>= 1) { s += __shfl_down(s, o); ss += __shfl_down(ss, o); }
  __shared__ float red[8];
  int wid = tid >> 6;
  if ((tid & 63) == 0) { red[wid] = s; red[4 + wid] = ss; }
  __syncthreads();
  float tot = red[0] + red[1] + red[2] + red[3];
  float tss = red[4] + red[5] + red[6] + red[7];
  float mean = tot * (1.f / C_);
  float var = tss * (1.f / C_) - mean * mean;
  float rstd = rsqrtf(var + 1e-5f);
  u16* op = out + (size_t)row * C_;
  op[tid]       = f2bf((v0 - mean) * rstd * g[tid]       + b[tid]);
  op[tid + 256] = f2bf((v1 - mean) * rstd * g[tid + 256] + b[tid + 256]);
  op[tid + 512] = f2bf((v2 - mean) * rstd * g[tid + 512] + b[tid + 512]);
}

// ---------------- GEMM (layer ops): BK=32, 3-deep ring + counted vmcnt (R5-proven) ----------------
template <int THREADS, int BM, int BN, int WM, int WN, int BIAS, int RELU, int OUTMODE, int SPLITK>
__global__ __launch_bounds__(THREADS) void gemm3(
    const u16* __restrict__ A, const u16* __restrict__ BT,
    const float* __restrict__ bias,
    u16* __restrict__ ob, float* __restrict__ fout, u16* __restrict__ vt,
    int N, int K) {
  constexpr int ALOADS = (BM * 64) / (THREADS * 16);
  constexpr int BLOADS = (BN * 64) / (THREADS * 16);
  constexpr int LDS_L = ALOADS + BLOADS;
  constexpr int MF = BM / (WM * 16);
  constexpr int NF = BN / (WN * 16);
  __shared__ __align__(16) u16 As[3][BM * 32];
  __shared__ __align__(16) u16 Bs[3][BN * 32];

  int tid = threadIdx.x;
  int lane = tid & 63, w = tid >> 6;
  int wm = w / WN, wn = w % WN;
  int rr = lane & 15, qg = lane >> 4;

  int gx = gridDim.x;
  int nwg = gx * gridDim.y;
  int flat = blockIdx.y * gx + blockIdx.x;
  int wg = xcd_swz(flat, nwg);
  int m0 = (wg % gx) * BM, n0 = (wg / gx) * BN;

  int kz = SPLITK > 1 ? blockIdx.z : 0;
  int Keff = SPLITK > 1 ? (K / SPLITK) : K;
  int kbase = kz * Keff;

  const u16* Aps[ALOADS];
  const u16* Bps[BLOADS];
#pragma unroll
  for (int i = 0; i < ALOADS; i++) {
    int idx = i * THREADS + tid;
    int row = idx >> 2;
    int chunk = (idx & 3) ^ ((row >> 1) & 3);
    Aps[i] = A + (size_t)(m0 + row) * K + chunk * 8 + kbase;
  }
#pragma unroll
  for (int i = 0; i < BLOADS; i++) {
    int idx = i * THREADS + tid;
    int row = idx >> 2;
    int chunk = (idx & 3) ^ ((row >> 1) & 3);
    Bps[i] = BT + (size_t)(n0 + row) * K + chunk * 8 + kbase;
  }

  auto stage = [&](int sl, int kk) {
#pragma unroll
    for (int i = 0; i < ALOADS; i++)
      gload16(Aps[i] + kk, (char*)As + (size_t)sl * BM * 64 + i * THREADS * 16 + w * 1024);
#pragma unroll
    for (int i = 0; i < BLOADS; i++)
      gload16(Bps[i] + kk, (char*)Bs + (size_t)sl * BN * 64 + i * THREADS * 16 + w * 1024);
  };

  floatx4 zero = {0.f, 0.f, 0.f, 0.f};
  floatx4 acc[MF][NF];
#pragma unroll
  for (int i = 0; i < MF; i++)
#pragma unroll
    for (int j = 0; j < NF; j++) acc[i][j] = zero;

  int NT = Keff >> 5;
  stage(0, 0);
  stage(1, 32);
  if constexpr (LDS_L == 2) VMW(2);
  else if constexpr (LDS_L == 3) VMW(3);
  else if constexpr (LDS_L == 4) VMW(4);
  else VMW(6);
  SBAR;
  SCHED0;

  int sqA = (qg ^ ((rr >> 1) & 3)) << 4;

  for (int t = 0; t < NT; ++t) {
    int sl = t % 3;
    if (t + 2 < NT) stage((t + 2) % 3, (t + 2) << 5);
    SCHED0;
    const char* Ab = (const char*)As + (size_t)sl * BM * 64;
    const char* Bb = (const char*)Bs + (size_t)sl * BN * 64;
    short8 af[MF], bf[NF];
#pragma unroll
    for (int i = 0; i < MF; i++)
      af[i] = *(const short8*)(Ab + ((wm * (BM / WM) + i * 16 + rr) << 6) + sqA);
#pragma unroll
    for (int j = 0; j < NF; j++)
      bf[j] = *(const short8*)(Bb + ((wn * (BN / WN) + j * 16 + rr) << 6) + sqA);
    __builtin_amdgcn_s_setprio(1);
#pragma unroll
    for (int i = 0; i < MF; i++)
#pragma unroll
      for (int j = 0; j < NF; j++)
        acc[i][j] = __builtin_amdgcn_mfma_f32_16x16x32_bf16(af[i], bf[j], acc[i][j], 0, 0, 0);
    __builtin_amdgcn_s_setprio(0);
    if (t < NT - 2) {
      if constexpr (LDS_L == 2) VMW(2);
      else if constexpr (LDS_L == 3) VMW(3);
      else if constexpr (LDS_L == 4) VMW(4);
      else VMW(6);
    } else if (t == NT - 2) VMW(0);
    if (t < NT - 1) { SBAR; SCHED0; }
  }

  int cb = n0 + wn * (BN / WN);
  int rb = m0 + wm * (BM / WM);
  bool isv = (OUTMODE == 3) && (n0 >= 1536);
#pragma unroll
  for (int i = 0; i < MF; i++) {
#pragma unroll
    for (int j = 0; j < NF; j++) {
      int col = cb + j * 16 + rr;
      float bv = 0.f;
      if (BIAS && kz == 0) bv = bias[col];
      float vals[4];
#pragma unroll
      for (int r = 0; r < 4; r++) {
        float val = acc[i][j][r] + bv;
        if (RELU) val = fmaxf(val, 0.f);
        vals[r] = val;
      }
      int row0 = rb + i * 16 + qg * 4;
      if (isv) {
        int colv = col - 1536;
        int bb = row0 >> 10, t0 = row0 & (T_ - 1);
        uint2 pk;
        pk.x = (unsigned int)f2bf(vals[0]) | ((unsigned int)f2bf(vals[1]) << 16);
        pk.y = (unsigned int)f2bf(vals[2]) | ((unsigned int)f2bf(vals[3]) << 16);
        *(uint2*)&vt[((size_t)bb * C_ + colv) * T_ + t0] = pk;
      } else {
#pragma unroll
        for (int r = 0; r < 4; r++) {
          size_t o = (size_t)(row0 + r) * N + col;
          if (OUTMODE == 0 || OUTMODE == 3) ob[o] = f2bf(vals[r]);
          else if (OUTMODE == 1) {
            if (SPLITK > 1) atomicAdd(&fout[o], vals[r]);
            else fout[o] += vals[r];
          } else fout[o] = vals[r];
        }
      }
    }
  }
}

// ---------------- 256x256 logits GEMM: m201-style 8-phase, plain scalar stores (R11, best) ----
__global__ __launch_bounds__(512) void gemm8(
    const u16* __restrict__ A, const u16* __restrict__ BT,
    const float* __restrict__ bias, float* __restrict__ fout, int N, int K) {
  __shared__ __align__(16) u16 As[2][2][128 * 64];
  __shared__ __align__(16) u16 Bs[2][2][128 * 64];
  int tid = threadIdx.x;
  int lane = tid & 63, w = tid >> 6;
  int wr = w >> 2, wc = w & 3;
  int rr = lane & 15, qg = lane >> 4;

  int gx = gridDim.x;
  int nwg = gx * gridDim.y;
  int flat = blockIdx.y * gx + blockIdx.x;
  int wg = xcd_swz(flat, nwg);
  int m0 = (wg % gx) * 256, n0 = (wg / gx) * 256;

  int la = tid >> 3;
  int sa = (((tid & 7) ^ (la & 7)) << 3);
  const u16* Ap0 = A + (size_t)(m0 + la) * K + sa;
  const u16* Ap1 = A + (size_t)(m0 + 128 + la) * K + sa;
  int lb0 = la, lb1 = 64 + la;
  const u16* Bp0 = BT + (size_t)(n0 + (lb0 >> 5) * 64 + (lb0 & 31)) * K + sa;
  const u16* Bp1 = BT + (size_t)(n0 + (lb1 >> 5) * 64 + (lb1 & 31)) * K + sa;

  auto stA = [&](int buf, int mh, int kt) {
    size_t off = (size_t)mh * 64 * K + kt * 64;
    gload16(Ap0 + off, (char*)&As[buf][mh][0] + w * 1024);
    gload16(Ap1 + off, (char*)&As[buf][mh][0] + 8192 + w * 1024);
  };
  auto stB = [&](int buf, int nh, int kt) {
    size_t off = (size_t)nh * 32 * K + kt * 64;
    gload16(Bp0 + off, (char*)&Bs[buf][nh][0] + w * 1024);
    gload16(Bp1 + off, (char*)&Bs[buf][nh][0] + 8192 + w * 1024);
  };
  auto stageOrd = [&](int buf, int h, int kt) {
    if (h == 0) stA(buf, 0, kt);
    else if (h == 1) stB(buf, 0, kt);
    else if (h == 2) stB(buf, 1, kt);
    else stA(buf, 1, kt);
  };

  floatx4 zero = {0.f, 0.f, 0.f, 0.f};
  floatx4 acc[8][4];
#pragma unroll
  for (int i = 0; i < 8; i++)
#pragma unroll
    for (int j = 0; j < 4; j++) acc[i][j] = zero;

  short8 a[2][4], b[2][2];
  int NKT = K >> 6;
  int NIT = NKT >> 1;

  stageOrd(0, 0, 0); stageOrd(0, 1, 0); stageOrd(0, 2, 0); stageOrd(0, 3, 0);
  VMW(4);
  SBAR;
  SCHED0;

  for (int it = 0; it < NIT; ++it) {
    int kt2 = it * 2;
    bool last = (it == NIT - 1);
#pragma unroll
    for (int p = 0; p < 8; ++p) {
      const int d = p >> 2;
      const int q = p & 3;
      const int mh = q >> 1, nh = q & 1;
      const char* Abp = (const char*)&As[d][mh][0];
      const char* Bbp = (const char*)&Bs[d][nh][0];
      if (q == 0 || q == 2) {
#pragma unroll
        for (int kk = 0; kk < 2; kk++)
#pragma unroll
          for (int i = 0; i < 4; i++) {
            int l = wr * 64 + i * 16 + rr;
            a[kk][i] = *(const short8*)(Abp + l * 128 + ((((kk << 2) + qg) ^ (rr & 7)) << 4));
          }
      }
#pragma unroll
      for (int kk = 0; kk < 2; kk++)
#pragma unroll
        for (int j = 0; j < 2; j++) {
          int l = wc * 32 + j * 16 + rr;
          b[kk][j] = *(const short8*)(Bbp + l * 128 + ((((kk << 2) + qg) ^ (rr & 7)) << 4));
        }
      if (p < 4) stageOrd(1, q, kt2 + 1);
      else if (!last) stageOrd(0, q, kt2 + 2);
      SCHED0;
      SBAR;
      LGKM0;
      SCHED0;
      __builtin_amdgcn_s_setprio(1);
#pragma unroll
      for (int kk = 0; kk < 2; kk++)
#pragma unroll
        for (int i = 0; i < 4; i++)
#pragma unroll
          for (int j = 0; j < 2; j++)
            acc[mh * 4 + i][nh * 2 + j] = __builtin_amdgcn_mfma_f32_16x16x32_bf16(
                a[kk][i], b[kk][j], acc[mh * 4 + i][nh * 2 + j], 0, 0, 0);
      __builtin_amdgcn_s_setprio(0);
      if (!last || p < 4) VMW(4);
      else if (p == 4) VMW(2);
      else if (p == 5) VMW(0);
      SBAR;
      SCHED0;
    }
  }

  int rbase = m0 + wr * 128;
  int cbase = n0 + wc * 64;
#pragma unroll
  for (int fi = 0; fi < 8; fi++) {
    int row0 = rbase + (fi >> 2) * 64 + (fi & 3) * 16 + qg * 4;
#pragma unroll
    for (int fj = 0; fj < 4; fj++) {
      int col = cbase + (fj >> 1) * 32 + (fj & 1) * 16 + rr;
      float bv = bias[col];
#pragma unroll
      for (int r = 0; r < 4; r++)
        fout[(size_t)(row0 + r) * N + col] = acc[fi][fj][r] + bv;
    }
  }
}

// ---------------- fused causal attention: 4-wave KV-split + online-softmax merge ----------------
__global__ __launch_bounds__(256) void attn_kernel(
    const u16* __restrict__ qkv, const u16* __restrict__ vt, u16* __restrict__ o) {
  __shared__ __align__(16) u16 P_s[4][16 * 48];
  __shared__ float mls[3][2][16];
  __shared__ float osm[3][16][64];
  int nwg = gridDim.x;
  int wg = xcd_swz(blockIdx.x, nwg);
  int qt = wg & 63;
  int h = (wg >> 6) % H_;
  int b = wg / (64 * H_);
  int q0 = qt << 4;
  int tid = threadIdx.x;
  int ws = tid >> 6;
  int lane = tid & 63;
  int rr = lane & 15, qg = lane >> 4, kq = qg << 3;

  const u16* qb = qkv + (size_t)(b * T_ + q0 + rr) * C3_ + h * 64;
  short8 qf0 = *(const short8*)(qb + kq);
  short8 qf1 = *(const short8*)(qb + 32 + kq);

  float m_r = -1e30f, l_r = 0.f;
  floatx4 zero = {0.f, 0.f, 0.f, 0.f};
  floatx4 oacc[4];
#pragma unroll
  for (int d = 0; d < 4; d++) oacc[d] = zero;

  const u16* kbase = qkv + (size_t)(b * T_) * C3_ + 768 + h * 64;
  const u16* vbase = vt + (size_t)(b * C_ + h * 64) * T_;

  for (int kt0 = ws * 32; kt0 <= q0 + 15; kt0 += 128) {
    floatx4 s[2];
#pragma unroll
    for (int c = 0; c < 2; c++) {
      const u16* kb = kbase + (size_t)(kt0 + c * 16 + rr) * C3_;
      short8 kf0 = *(const short8*)(kb + kq);
      short8 kf1 = *(const short8*)(kb + 32 + kq);
      floatx4 z = zero;
      z = __builtin_amdgcn_mfma_f32_16x16x32_bf16(kf0, qf0, z, 0, 0, 0);
      z = __builtin_amdgcn_mfma_f32_16x16x32_bf16(kf1, qf1, z, 0, 0, 0);
      s[c] = z;
    }
    int qpos = q0 + rr;
    float p[2][4];
    float mx = -1e30f;
#pragma unroll
    for (int c = 0; c < 2; c++)
#pragma unroll
      for (int r = 0; r < 4; r++) {
        int kpos = kt0 + c * 16 + qg * 4 + r;
        float val = s[c][r] * 0.125f;
        val = (kpos <= qpos) ? val : -1e30f;
        p[c][r] = val;
        mx = fmaxf(mx, val);
      }
    mx = fmaxf(mx, __shfl_xor(mx, 16));
    mx = fmaxf(mx, __shfl_xor(mx, 32));
    float mn = fmaxf(m_r, mx);
    float escL = exp2f((m_r - mn) * 1.44269504f);
    m_r = mn;
    float ps = 0.f;
#pragma unroll
    for (int c = 0; c < 2; c++)
#pragma unroll
      for (int r = 0; r < 4; r++) {
        float pv = exp2f((p[c][r] - mn) * 1.44269504f);
        p[c][r] = pv;
        ps += pv;
      }
    ps += __shfl_xor(ps, 16);
    ps += __shfl_xor(ps, 32);
    l_r = l_r * escL + ps;
#pragma unroll
    for (int c = 0; c < 2; c++) {
      unsigned int u0 = (unsigned int)f2bf(p[c][0]) | ((unsigned int)f2bf(p[c][1]) << 16);
      unsigned int u1 = (unsigned int)f2bf(p[c][2]) | ((unsigned int)f2bf(p[c][3]) << 16);
      uint2 pk; pk.x = u0; pk.y = u1;
      *(uint2*)&P_s[ws][rr * 48 + c * 16 + qg * 4] = pk;
    }
    float er[4];
#pragma unroll
    for (int r = 0; r < 4; r++) er[r] = __shfl(escL, qg * 4 + r);
#pragma unroll
    for (int d = 0; d < 4; d++)
#pragma unroll
      for (int r = 0; r < 4; r++) oacc[d][r] *= er[r];
    short8 pa = *(const short8*)&P_s[ws][rr * 48 + kq];
#pragma unroll
    for (int d = 0; d < 4; d++) {
      short8 vf = *(const short8*)(vbase + (size_t)(d * 16 + rr) * T_ + kt0 + kq);
      oacc[d] = __builtin_amdgcn_mfma_f32_16x16x32_bf16(pa, vf, oacc[d], 0, 0, 0);
    }
  }

  // partials -> LDS (waves 1..3); merge in wave 0
  if (ws != 0) {
    if (qg == 0) { mls[ws - 1][0][rr] = m_r; mls[ws - 1][1][rr] = l_r; }
#pragma unroll
    for (int d = 0; d < 4; d++)
#pragma unroll
      for (int r = 0; r < 4; r++)
        osm[ws - 1][qg * 4 + r][d * 16 + rr] = oacc[d][r];
  }
  __syncthreads();
  if (ws == 0) {
#pragma unroll
    for (int s2 = 0; s2 < 3; s2++) {
      float mw = mls[s2][0][rr];
      float lw = mls[s2][1][rr];
      float mn = fmaxf(m_r, mw);
      float e0 = exp2f((m_r - mn) * 1.44269504f);
      float e1 = exp2f((mw - mn) * 1.44269504f);
      m_r = mn;
      l_r = l_r * e0 + lw * e1;
      float er0[4], er1[4];
#pragma unroll
      for (int r = 0; r < 4; r++) {
        er0[r] = __shfl(e0, qg * 4 + r);
        er1[r] = __shfl(e1, qg * 4 + r);
      }
#pragma unroll
      for (int d = 0; d < 4; d++)
#pragma unroll
        for (int r = 0; r < 4; r++)
          oacc[d][r] = oacc[d][r] * er0[r] + osm[s2][qg * 4 + r][d * 16 + rr] * er1[r];
    }
    float lb[4];
#pragma unroll
    for (int r = 0; r < 4; r++) lb[r] = __shfl(l_r, qg * 4 + r);
    u16* obp = o + (size_t)(b * T_ + q0) * C_ + h * 64;
#pragma unroll
    for (int d = 0; d < 4; d++)
#pragma unroll
      for (int r = 0; r < 4; r++) {
        int row = qg * 4 + r;
        obp[(size_t)row * C_ + d * 16 + rr] = f2bf(oacc[d][r] / lb[r]);
      }
  }
}

extern "C" void kernel_launch(void* const* d_in, const int* in_sizes, int n_in,
                              void* d_out, int out_size, void* d_ws, size_t ws_size,
                              hipStream_t stream) {
  (void)in_sizes; (void)n_in; (void)out_size; (void)ws_size;
  const int*   xidx = (const int*)d_in[0];
  const float* tok  = (const float*)d_in[1];
  const float* pos  = (const float*)d_in[2];
  const float* ln1g = (const float*)d_in[3];
  const float* ln1b = (const float*)d_in[4];
  const float* wq   = (const float*)d_in[5];
  const float* wk   = (const float*)d_in[6];
  const float* wv   = (const float*)d_in[7];
  const float* wo   = (const float*)d_in[8];
  const float* bo   = (const float*)d_in[9];
  const float* ln2g = (const float*)d_in[10];
  const float* ln2b = (const float*)d_in[11];
  const float* w1   = (const float*)d_in[12];
  const float* b1   = (const float*)d_in[13];
  const float* w2   = (const float*)d_in[14];
  const float* b2   = (const float*)d_in[15];
  const float* lnfg = (const float*)d_in[16];
  const float* lnfb = (const float*)d_in[17];
  const float* wp   = (const float*)d_in[18];
  const float* bp   = (const float*)d_in[19];

  char* ws = (char*)d_ws;
  size_t off = 0;
  auto alloc = [&](size_t bytes) { char* p = ws + off; off += (bytes + 255) & ~(size_t)255; return p; };
  u16* wqkvT = (u16*)alloc((size_t)L_ * 3 * C_ * C_ * 2);   // [l][3C][C]
  u16* woT = (u16*)alloc((size_t)L_ * C_ * C_ * 2);
  u16* w1T = (u16*)alloc((size_t)L_ * C_ * F_ * 2);
  u16* w2T = (u16*)alloc((size_t)L_ * C_ * F_ * 2);
  u16* wpT = (u16*)alloc((size_t)C_ * V_ * 2);
  float* x = (float*)alloc((size_t)M_ * C_ * 4);
  u16* hb   = (u16*)alloc((size_t)M_ * C_ * 2);
  u16* qkvb = (u16*)alloc((size_t)M_ * C3_ * 2);
  u16* vtb  = (u16*)alloc((size_t)M_ * C_ * 2);
  u16* aob  = (u16*)alloc((size_t)M_ * C_ * 2);
  u16* mb   = (u16*)alloc((size_t)M_ * F_ * 2);

  dim3 blk(256);
  size_t CC = (size_t)C_ * C_, CF = (size_t)C_ * F_;
  transpose4_qkvo<<<dim3(C_ / 32, C_ / 32, L_ * 4), blk, 0, stream>>>(
      wq, wk, wv, wo, wqkvT, woT);
  transpose_f32_bf16<<<dim3(F_ / 32, C_ / 32, L_), blk, 0, stream>>>(w1, w1T, C_, F_, CF, CF);
  transpose_f32_bf16<<<dim3(C_ / 32, F_ / 32, L_), blk, 0, stream>>>(w2, w2T, F_, C_, CF, CF);
  transpose_f32_bf16<<<dim3(V_ / 32, C_ / 32, 1), blk, 0, stream>>>(wp, wpT, C_, V_, 0, 0);
  embed_ln<<<M_, blk, 0, stream>>>(xidx, tok, pos, ln1g, ln1b, x, hb);

  for (int l = 0; l < L_; ++l) {
    size_t wOff = (size_t)l * 3 * CC;
    size_t oOff = (size_t)l * CC;
    size_t fOff = (size_t)l * CF;
    if (l > 0)
      ln_kernel<<<M_, blk, 0, stream>>>(x, ln1g + l * C_, ln1b + l * C_, hb);
    gemm3<256, 128, 128, 2, 2, 0, 0, 3, 1><<<dim3(M_ / 128, C3_ / 128), 256, 0, stream>>>(
        hb, wqkvT + wOff, nullptr, qkvb, nullptr, vtb, C3_, C_);
    attn_kernel<<<B_ * H_ * (T_ / 16), dim3(256), 0, stream>>>(qkvb, vtb, aob);
    gemm3<256, 128, 128, 2, 2, 1, 0, 1, 2><<<dim3(M_ / 128, C_ / 128, 2), 256, 0, stream>>>(
        aob, woT + oOff, bo + l * C_, nullptr, x, nullptr, C_, C_);
    ln_kernel<<<M_, blk, 0, stream>>>(x, ln2g + l * C_, ln2b + l * C_, hb);
    gemm3<256, 128, 128, 2, 2, 1, 1, 0, 1><<<dim3(M_ / 128, F_ / 128), 256, 0, stream>>>(
        hb, w1T + fOff, b1 + l * F_, mb, nullptr, nullptr, F_, C_);
    gemm3<256, 128, 128, 2, 2, 1, 0, 1, 2><<<dim3(M_ / 128, C_ / 128, 2), 256, 0, stream>>>(
        mb, w2T + fOff, b2 + l * C_, nullptr, x, nullptr, C_, F_);
  }
  ln_kernel<<<M_, blk, 0, stream>>>(x, lnfg, lnfb, hb);
  gemm8<<<dim3(M_ / 256, V_ / 256), 512, 0, stream>>>(
      hb, wpT, bp, (float*)d_out, V_, C_);
}

// Round 16
// 1004.015 us; speedup vs baseline: 1.0585x; 1.0215x over previous
//
#include <hip/hip_runtime.h>
#include <stdint.h>

#define DEV __device__ __forceinline__

typedef unsigned short u16;
typedef __attribute__((ext_vector_type(8))) short short8;
typedef __attribute__((ext_vector_type(4))) float floatx4;

#define B_ 2
#define T_ 1024
#define C_ 768
#define H_ 12
#define L_ 6
#define V_ 32000
#define F_ 3072
#define M_ 2048   // B*T
#define C3_ 2304  // 3*C (packed qkv)

#define VMW(n) asm volatile("s_waitcnt vmcnt(" #n ")" ::: "memory")
#define LGKM0 asm volatile("s_waitcnt lgkmcnt(0)" ::: "memory")
#define SBAR __builtin_amdgcn_s_barrier()
#define SCHED0 __builtin_amdgcn_sched_barrier(0)

DEV u16 f2bf(float f) {
  unsigned int u; __builtin_memcpy(&u, &f, 4);
  u += 0x7FFFu + ((u >> 16) & 1u);   // round-to-nearest-even
  return (u16)(u >> 16);
}

// async global->LDS, 16B per lane. LDS ptr wave-uniform; HW adds lane*16.
DEV void gload16(const void* g, void* l) {
  __builtin_amdgcn_global_load_lds(
      (__attribute__((address_space(1))) void*)(uintptr_t)g,
      (__attribute__((address_space(3))) void*)(unsigned int)(uintptr_t)l,
      16, 0, 0);
}

// bijective XCD swizzle (m204)
DEV int xcd_swz(int flat, int nwg) {
  int q = nwg >> 3, r = nwg & 7;
  int xcd = flat & 7, sid = flat >> 3;
  return (xcd < r ? xcd * (q + 1) : r * (q + 1) + (xcd - r) * q) + sid;
}

// ---------------- transpose + f32->bf16 convert: src[z][R][Cc] -> dst[Cc][R] ----------------
__global__ __launch_bounds__(256) void transpose_f32_bf16(
    const float* __restrict__ src, u16* __restrict__ dst, int R, int Cc,
    size_t src_z, size_t dst_z) {
  __shared__ float tile[32][33];
  const float* s = src + (size_t)blockIdx.z * src_z;
  u16* d = dst + (size_t)blockIdx.z * dst_z;
  int c0 = blockIdx.x * 32, r0 = blockIdx.y * 32;
  int tx = threadIdx.x & 31, ty = threadIdx.x >> 5;
#pragma unroll
  for (int i = 0; i < 4; i++)
    tile[ty + 8 * i][tx] = s[(size_t)(r0 + ty + 8 * i) * Cc + (c0 + tx)];
  __syncthreads();
#pragma unroll
  for (int i = 0; i < 4; i++)
    d[(size_t)(c0 + ty + 8 * i) * R + (r0 + tx)] = f2bf(tile[tx][ty + 8 * i]);
}

// ---------------- batched CxC transpose for wq/wk/wv/wo (z = l*4 + wsel) ----------------
__global__ __launch_bounds__(256) void transpose4_qkvo(
    const float* __restrict__ wq, const float* __restrict__ wk,
    const float* __restrict__ wv, const float* __restrict__ wo,
    u16* __restrict__ wqkvT, u16* __restrict__ woT) {
  __shared__ float tile[32][33];
  int z = blockIdx.z;
  int l = z >> 2, wsel = z & 3;
  size_t CC = (size_t)C_ * C_;
  const float* s = (wsel == 0 ? wq : wsel == 1 ? wk : wsel == 2 ? wv : wo) + (size_t)l * CC;
  u16* d = (wsel < 3) ? (wqkvT + (size_t)l * 3 * CC + (size_t)wsel * CC)
                      : (woT + (size_t)l * CC);
  int c0 = blockIdx.x * 32, r0 = blockIdx.y * 32;
  int tx = threadIdx.x & 31, ty = threadIdx.x >> 5;
#pragma unroll
  for (int i = 0; i < 4; i++)
    tile[ty + 8 * i][tx] = s[(size_t)(r0 + ty + 8 * i) * C_ + (c0 + tx)];
  __syncthreads();
#pragma unroll
  for (int i = 0; i < 4; i++)
    d[(size_t)(c0 + ty + 8 * i) * C_ + (r0 + tx)] = f2bf(tile[tx][ty + 8 * i]);
}

// ---------------- fused embedding + layer-0 LN1: writes x (f32) and hb (bf16) ----------------
__global__ __launch_bounds__(256) void embed_ln(
    const int* __restrict__ idx, const float* __restrict__ tok,
    const float* __restrict__ pos, const float* __restrict__ g,
    const float* __restrict__ b, float* __restrict__ x, u16* __restrict__ out) {
  int row = blockIdx.x;
  int t = row & (T_ - 1);
  int tk = idx[row];
  const float* tp = tok + (size_t)tk * C_;
  const float* pp = pos + (size_t)t * C_;
  float* xp = x + (size_t)row * C_;
  int tid = threadIdx.x;
  float v0 = tp[tid] + pp[tid];
  float v1 = tp[tid + 256] + pp[tid + 256];
  float v2 = tp[tid + 512] + pp[tid + 512];
  xp[tid] = v0; xp[tid + 256] = v1; xp[tid + 512] = v2;
  float s = v0 + v1 + v2;
  float ss = v0 * v0 + v1 * v1 + v2 * v2;
#pragma unroll
  for (int o = 32; o > 0; o >>= 1) { s += __shfl_down(s, o); ss += __shfl_down(ss, o); }
  __shared__ float red[8];
  int wid = tid >> 6;
  if ((tid & 63) == 0) { red[wid] = s; red[4 + wid] = ss; }
  __syncthreads();
  float tot = red[0] + red[1] + red[2] + red[3];
  float tss = red[4] + red[5] + red[6] + red[7];
  float mean = tot * (1.f / C_);
  float var = tss * (1.f / C_) - mean * mean;
  float rstd = rsqrtf(var + 1e-5f);
  u16* op = out + (size_t)row * C_;
  op[tid]       = f2bf((v0 - mean) * rstd * g[tid]       + b[tid]);
  op[tid + 256] = f2bf((v1 - mean) * rstd * g[tid + 256] + b[tid + 256]);
  op[tid + 512] = f2bf((v2 - mean) * rstd * g[tid + 512] + b[tid + 512]);
}

// ---------------- fused residual-sum + layernorm: x += p0 + p1; hb = LN(x) ----------------
__global__ __launch_bounds__(256) void ln_sum(
    float* __restrict__ x, const float* __restrict__ p0, const float* __restrict__ p1,
    const float* __restrict__ g, const float* __restrict__ b, u16* __restrict__ out) {
  int row = blockIdx.x;
  int tid = threadIdx.x;
  size_t base = (size_t)row * C_;
  float* xp = x + base;
  const float* q0 = p0 + base;
  const float* q1 = p1 + base;
  float v0 = xp[tid]       + q0[tid]       + q1[tid];
  float v1 = xp[tid + 256] + q0[tid + 256] + q1[tid + 256];
  float v2 = xp[tid + 512] + q0[tid + 512] + q1[tid + 512];
  xp[tid] = v0; xp[tid + 256] = v1; xp[tid + 512] = v2;
  float s = v0 + v1 + v2;
  float ss = v0 * v0 + v1 * v1 + v2 * v2;
#pragma unroll
  for (int o = 32; o > 0; o >>= 1) { s += __shfl_down(s, o); ss += __shfl_down(ss, o); }
  __shared__ float red[8];
  int wid = tid >> 6;
  if ((tid & 63) == 0) { red[wid] = s; red[4 + wid] = ss; }
  __syncthreads();
  float tot = red[0] + red[1] + red[2] + red[3];
  float tss = red[4] + red[5] + red[6] + red[7];
  float mean = tot * (1.f / C_);
  float var = tss * (1.f / C_) - mean * mean;
  float rstd = rsqrtf(var + 1e-5f);
  u16* op = out + (size_t)row * C_;
  op[tid]       = f2bf((v0 - mean) * rstd * g[tid]       + b[tid]);
  op[tid + 256] = f2bf((v1 - mean) * rstd * g[tid + 256] + b[tid + 256]);
  op[tid + 512] = f2bf((v2 - mean) * rstd * g[tid + 512] + b[tid + 512]);
}

// ---------------- GEMM (layer ops): BK=32, 3-deep ring + counted vmcnt (R5-proven) ----------------
// OUTMODE: 0 = bf16 out, 2 = f32 out, 3 = qkv mode (V^T fused),
//          4 = f32 partial slab (fout + kz*M_*N), no atomics; bias on kz==0
template <int THREADS, int BM, int BN, int WM, int WN, int BIAS, int RELU, int OUTMODE, int SPLITK>
__global__ __launch_bounds__(THREADS) void gemm3(
    const u16* __restrict__ A, const u16* __restrict__ BT,
    const float* __restrict__ bias,
    u16* __restrict__ ob, float* __restrict__ fout, u16* __restrict__ vt,
    int N, int K) {
  constexpr int ALOADS = (BM * 64) / (THREADS * 16);
  constexpr int BLOADS = (BN * 64) / (THREADS * 16);
  constexpr int LDS_L = ALOADS + BLOADS;
  constexpr int MF = BM / (WM * 16);
  constexpr int NF = BN / (WN * 16);
  __shared__ __align__(16) u16 As[3][BM * 32];
  __shared__ __align__(16) u16 Bs[3][BN * 32];

  int tid = threadIdx.x;
  int lane = tid & 63, w = tid >> 6;
  int wm = w / WN, wn = w % WN;
  int rr = lane & 15, qg = lane >> 4;

  int gx = gridDim.x;
  int nwg = gx * gridDim.y;
  int flat = blockIdx.y * gx + blockIdx.x;
  int wg = xcd_swz(flat, nwg);
  int m0 = (wg % gx) * BM, n0 = (wg / gx) * BN;

  int kz = SPLITK > 1 ? blockIdx.z : 0;
  int Keff = SPLITK > 1 ? (K / SPLITK) : K;
  int kbase = kz * Keff;

  const u16* Aps[ALOADS];
  const u16* Bps[BLOADS];
#pragma unroll
  for (int i = 0; i < ALOADS; i++) {
    int idx = i * THREADS + tid;
    int row = idx >> 2;
    int chunk = (idx & 3) ^ ((row >> 1) & 3);
    Aps[i] = A + (size_t)(m0 + row) * K + chunk * 8 + kbase;
  }
#pragma unroll
  for (int i = 0; i < BLOADS; i++) {
    int idx = i * THREADS + tid;
    int row = idx >> 2;
    int chunk = (idx & 3) ^ ((row >> 1) & 3);
    Bps[i] = BT + (size_t)(n0 + row) * K + chunk * 8 + kbase;
  }

  auto stage = [&](int sl, int kk) {
#pragma unroll
    for (int i = 0; i < ALOADS; i++)
      gload16(Aps[i] + kk, (char*)As + (size_t)sl * BM * 64 + i * THREADS * 16 + w * 1024);
#pragma unroll
    for (int i = 0; i < BLOADS; i++)
      gload16(Bps[i] + kk, (char*)Bs + (size_t)sl * BN * 64 + i * THREADS * 16 + w * 1024);
  };

  floatx4 zero = {0.f, 0.f, 0.f, 0.f};
  floatx4 acc[MF][NF];
#pragma unroll
  for (int i = 0; i < MF; i++)
#pragma unroll
    for (int j = 0; j < NF; j++) acc[i][j] = zero;

  int NT = Keff >> 5;
  stage(0, 0);
  stage(1, 32);
  if constexpr (LDS_L == 2) VMW(2);
  else if constexpr (LDS_L == 3) VMW(3);
  else if constexpr (LDS_L == 4) VMW(4);
  else VMW(6);
  SBAR;
  SCHED0;

  int sqA = (qg ^ ((rr >> 1) & 3)) << 4;

  for (int t = 0; t < NT; ++t) {
    int sl = t % 3;
    if (t + 2 < NT) stage((t + 2) % 3, (t + 2) << 5);
    SCHED0;
    const char* Ab = (const char*)As + (size_t)sl * BM * 64;
    const char* Bb = (const char*)Bs + (size_t)sl * BN * 64;
    short8 af[MF], bf[NF];
#pragma unroll
    for (int i = 0; i < MF; i++)
      af[i] = *(const short8*)(Ab + ((wm * (BM / WM) + i * 16 + rr) << 6) + sqA);
#pragma unroll
    for (int j = 0; j < NF; j++)
      bf[j] = *(const short8*)(Bb + ((wn * (BN / WN) + j * 16 + rr) << 6) + sqA);
    __builtin_amdgcn_s_setprio(1);
#pragma unroll
    for (int i = 0; i < MF; i++)
#pragma unroll
      for (int j = 0; j < NF; j++)
        acc[i][j] = __builtin_amdgcn_mfma_f32_16x16x32_bf16(af[i], bf[j], acc[i][j], 0, 0, 0);
    __builtin_amdgcn_s_setprio(0);
    if (t < NT - 2) {
      if constexpr (LDS_L == 2) VMW(2);
      else if constexpr (LDS_L == 3) VMW(3);
      else if constexpr (LDS_L == 4) VMW(4);
      else VMW(6);
    } else if (t == NT - 2) VMW(0);
    if (t < NT - 1) { SBAR; SCHED0; }
  }

  int cb = n0 + wn * (BN / WN);
  int rb = m0 + wm * (BM / WM);
  bool isv = (OUTMODE == 3) && (n0 >= 1536);
  float* fo = fout;
  if (OUTMODE == 4) fo = fout + (size_t)kz * M_ * N;
#pragma unroll
  for (int i = 0; i < MF; i++) {
#pragma unroll
    for (int j = 0; j < NF; j++) {
      int col = cb + j * 16 + rr;
      float bv = 0.f;
      if (BIAS && kz == 0) bv = bias[col];
      float vals[4];
#pragma unroll
      for (int r = 0; r < 4; r++) {
        float val = acc[i][j][r] + bv;
        if (RELU) val = fmaxf(val, 0.f);
        vals[r] = val;
      }
      int row0 = rb + i * 16 + qg * 4;
      if (isv) {
        int colv = col - 1536;
        int bb = row0 >> 10, t0 = row0 & (T_ - 1);
        uint2 pk;
        pk.x = (unsigned int)f2bf(vals[0]) | ((unsigned int)f2bf(vals[1]) << 16);
        pk.y = (unsigned int)f2bf(vals[2]) | ((unsigned int)f2bf(vals[3]) << 16);
        *(uint2*)&vt[((size_t)bb * C_ + colv) * T_ + t0] = pk;
      } else {
#pragma unroll
        for (int r = 0; r < 4; r++) {
          size_t o = (size_t)(row0 + r) * N + col;
          if (OUTMODE == 0 || OUTMODE == 3) ob[o] = f2bf(vals[r]);
          else fo[o] = vals[r];
        }
      }
    }
  }
}

// ---------------- 256x256 logits GEMM: m201-style 8-phase, plain scalar stores (converged) ----
__global__ __launch_bounds__(512) void gemm8(
    const u16* __restrict__ A, const u16* __restrict__ BT,
    const float* __restrict__ bias, float* __restrict__ fout, int N, int K) {
  __shared__ __align__(16) u16 As[2][2][128 * 64];
  __shared__ __align__(16) u16 Bs[2][2][128 * 64];
  int tid = threadIdx.x;
  int lane = tid & 63, w = tid >> 6;
  int wr = w >> 2, wc = w & 3;
  int rr = lane & 15, qg = lane >> 4;

  int gx = gridDim.x;
  int nwg = gx * gridDim.y;
  int flat = blockIdx.y * gx + blockIdx.x;
  int wg = xcd_swz(flat, nwg);
  int m0 = (wg % gx) * 256, n0 = (wg / gx) * 256;

  int la = tid >> 3;
  int sa = (((tid & 7) ^ (la & 7)) << 3);
  const u16* Ap0 = A + (size_t)(m0 + la) * K + sa;
  const u16* Ap1 = A + (size_t)(m0 + 128 + la) * K + sa;
  int lb0 = la, lb1 = 64 + la;
  const u16* Bp0 = BT + (size_t)(n0 + (lb0 >> 5) * 64 + (lb0 & 31)) * K + sa;
  const u16* Bp1 = BT + (size_t)(n0 + (lb1 >> 5) * 64 + (lb1 & 31)) * K + sa;

  auto stA = [&](int buf, int mh, int kt) {
    size_t off = (size_t)mh * 64 * K + kt * 64;
    gload16(Ap0 + off, (char*)&As[buf][mh][0] + w * 1024);
    gload16(Ap1 + off, (char*)&As[buf][mh][0] + 8192 + w * 1024);
  };
  auto stB = [&](int buf, int nh, int kt) {
    size_t off = (size_t)nh * 32 * K + kt * 64;
    gload16(Bp0 + off, (char*)&Bs[buf][nh][0] + w * 1024);
    gload16(Bp1 + off, (char*)&Bs[buf][nh][0] + 8192 + w * 1024);
  };
  auto stageOrd = [&](int buf, int h, int kt) {
    if (h == 0) stA(buf, 0, kt);
    else if (h == 1) stB(buf, 0, kt);
    else if (h == 2) stB(buf, 1, kt);
    else stA(buf, 1, kt);
  };

  floatx4 zero = {0.f, 0.f, 0.f, 0.f};
  floatx4 acc[8][4];
#pragma unroll
  for (int i = 0; i < 8; i++)
#pragma unroll
    for (int j = 0; j < 4; j++) acc[i][j] = zero;

  short8 a[2][4], b[2][2];
  int NKT = K >> 6;
  int NIT = NKT >> 1;

  stageOrd(0, 0, 0); stageOrd(0, 1, 0); stageOrd(0, 2, 0); stageOrd(0, 3, 0);
  VMW(4);
  SBAR;
  SCHED0;

  for (int it = 0; it < NIT; ++it) {
    int kt2 = it * 2;
    bool last = (it == NIT - 1);
#pragma unroll
    for (int p = 0; p < 8; ++p) {
      const int d = p >> 2;
      const int q = p & 3;
      const int mh = q >> 1, nh = q & 1;
      const char* Abp = (const char*)&As[d][mh][0];
      const char* Bbp = (const char*)&Bs[d][nh][0];
      if (q == 0 || q == 2) {
#pragma unroll
        for (int kk = 0; kk < 2; kk++)
#pragma unroll
          for (int i = 0; i < 4; i++) {
            int l = wr * 64 + i * 16 + rr;
            a[kk][i] = *(const short8*)(Abp + l * 128 + ((((kk << 2) + qg) ^ (rr & 7)) << 4));
          }
      }
#pragma unroll
      for (int kk = 0; kk < 2; kk++)
#pragma unroll
        for (int j = 0; j < 2; j++) {
          int l = wc * 32 + j * 16 + rr;
          b[kk][j] = *(const short8*)(Bbp + l * 128 + ((((kk << 2) + qg) ^ (rr & 7)) << 4));
        }
      if (p < 4) stageOrd(1, q, kt2 + 1);
      else if (!last) stageOrd(0, q, kt2 + 2);
      SCHED0;
      SBAR;
      LGKM0;
      SCHED0;
      __builtin_amdgcn_s_setprio(1);
#pragma unroll
      for (int kk = 0; kk < 2; kk++)
#pragma unroll
        for (int i = 0; i < 4; i++)
#pragma unroll
          for (int j = 0; j < 2; j++)
            acc[mh * 4 + i][nh * 2 + j] = __builtin_amdgcn_mfma_f32_16x16x32_bf16(
                a[kk][i], b[kk][j], acc[mh * 4 + i][nh * 2 + j], 0, 0, 0);
      __builtin_amdgcn_s_setprio(0);
      if (!last || p < 4) VMW(4);
      else if (p == 4) VMW(2);
      else if (p == 5) VMW(0);
      SBAR;
      SCHED0;
    }
  }

  int rbase = m0 + wr * 128;
  int cbase = n0 + wc * 64;
#pragma unroll
  for (int fi = 0; fi < 8; fi++) {
    int row0 = rbase + (fi >> 2) * 64 + (fi & 3) * 16 + qg * 4;
#pragma unroll
    for (int fj = 0; fj < 4; fj++) {
      int col = cbase + (fj >> 1) * 32 + (fj & 1) * 16 + rr;
      float bv = bias[col];
#pragma unroll
      for (int r = 0; r < 4; r++)
        fout[(size_t)(row0 + r) * N + col] = acc[fi][fj][r] + bv;
    }
  }
}

// ---------------- fused causal attention: 4-wave KV-split + online-softmax merge ----------------
__global__ __launch_bounds__(256) void attn_kernel(
    const u16* __restrict__ qkv, const u16* __restrict__ vt, u16* __restrict__ o) {
  __shared__ __align__(16) u16 P_s[4][16 * 48];
  __shared__ float mls[3][2][16];
  __shared__ float osm[3][16][64];
  int nwg = gridDim.x;
  int wg = xcd_swz(blockIdx.x, nwg);
  int qt = wg & 63;
  int h = (wg >> 6) % H_;
  int b = wg / (64 * H_);
  int q0 = qt << 4;
  int tid = threadIdx.x;
  int ws = tid >> 6;
  int lane = tid & 63;
  int rr = lane & 15, qg = lane >> 4, kq = qg << 3;

  const u16* qb = qkv + (size_t)(b * T_ + q0 + rr) * C3_ + h * 64;
  short8 qf0 = *(const short8*)(qb + kq);
  short8 qf1 = *(const short8*)(qb + 32 + kq);

  float m_r = -1e30f, l_r = 0.f;
  floatx4 zero = {0.f, 0.f, 0.f, 0.f};
  floatx4 oacc[4];
#pragma unroll
  for (int d = 0; d < 4; d++) oacc[d] = zero;

  const u16* kbase = qkv + (size_t)(b * T_) * C3_ + 768 + h * 64;
  const u16* vbase = vt + (size_t)(b * C_ + h * 64) * T_;

  for (int kt0 = ws * 32; kt0 <= q0 + 15; kt0 += 128) {
    floatx4 s[2];
#pragma unroll
    for (int c = 0; c < 2; c++) {
      const u16* kb = kbase + (size_t)(kt0 + c * 16 + rr) * C3_;
      short8 kf0 = *(const short8*)(kb + kq);
      short8 kf1 = *(const short8*)(kb + 32 + kq);
      floatx4 z = zero;
      z = __builtin_amdgcn_mfma_f32_16x16x32_bf16(kf0, qf0, z, 0, 0, 0);
      z = __builtin_amdgcn_mfma_f32_16x16x32_bf16(kf1, qf1, z, 0, 0, 0);
      s[c] = z;
    }
    int qpos = q0 + rr;
    float p[2][4];
    float mx = -1e30f;
#pragma unroll
    for (int c = 0; c < 2; c++)
#pragma unroll
      for (int r = 0; r < 4; r++) {
        int kpos = kt0 + c * 16 + qg * 4 + r;
        float val = s[c][r] * 0.125f;
        val = (kpos <= qpos) ? val : -1e30f;
        p[c][r] = val;
        mx = fmaxf(mx, val);
      }
    mx = fmaxf(mx, __shfl_xor(mx, 16));
    mx = fmaxf(mx, __shfl_xor(mx, 32));
    float mn = fmaxf(m_r, mx);
    float escL = exp2f((m_r - mn) * 1.44269504f);
    m_r = mn;
    float ps = 0.f;
#pragma unroll
    for (int c = 0; c < 2; c++)
#pragma unroll
      for (int r = 0; r < 4; r++) {
        float pv = exp2f((p[c][r] - mn) * 1.44269504f);
        p[c][r] = pv;
        ps += pv;
      }
    ps += __shfl_xor(ps, 16);
    ps += __shfl_xor(ps, 32);
    l_r = l_r * escL + ps;
#pragma unroll
    for (int c = 0; c < 2; c++) {
      unsigned int u0 = (unsigned int)f2bf(p[c][0]) | ((unsigned int)f2bf(p[c][1]) << 16);
      unsigned int u1 = (unsigned int)f2bf(p[c][2]) | ((unsigned int)f2bf(p[c][3]) << 16);
      uint2 pk; pk.x = u0; pk.y = u1;
      *(uint2*)&P_s[ws][rr * 48 + c * 16 + qg * 4] = pk;
    }
    float er[4];
#pragma unroll
    for (int r = 0; r < 4; r++) er[r] = __shfl(escL, qg * 4 + r);
#pragma unroll
    for (int d = 0; d < 4; d++)
#pragma unroll
      for (int r = 0; r < 4; r++) oacc[d][r] *= er[r];
    short8 pa = *(const short8*)&P_s[ws][rr * 48 + kq];
#pragma unroll
    for (int d = 0; d < 4; d++) {
      short8 vf = *(const short8*)(vbase + (size_t)(d * 16 + rr) * T_ + kt0 + kq);
      oacc[d] = __builtin_amdgcn_mfma_f32_16x16x32_bf16(pa, vf, oacc[d], 0, 0, 0);
    }
  }

  // partials -> LDS (waves 1..3); merge in wave 0
  if (ws != 0) {
    if (qg == 0) { mls[ws - 1][0][rr] = m_r; mls[ws - 1][1][rr] = l_r; }
#pragma unroll
    for (int d = 0; d < 4; d++)
#pragma unroll
      for (int r = 0; r < 4; r++)
        osm[ws - 1][qg * 4 + r][d * 16 + rr] = oacc[d][r];
  }
  __syncthreads();
  if (ws == 0) {
#pragma unroll
    for (int s2 = 0; s2 < 3; s2++) {
      float mw = mls[s2][0][rr];
      float lw = mls[s2][1][rr];
      float mn = fmaxf(m_r, mw);
      float e0 = exp2f((m_r - mn) * 1.44269504f);
      float e1 = exp2f((mw - mn) * 1.44269504f);
      m_r = mn;
      l_r = l_r * e0 + lw * e1;
      float er0[4], er1[4];
#pragma unroll
      for (int r = 0; r < 4; r++) {
        er0[r] = __shfl(e0, qg * 4 + r);
        er1[r] = __shfl(e1, qg * 4 + r);
      }
#pragma unroll
      for (int d = 0; d < 4; d++)
#pragma unroll
        for (int r = 0; r < 4; r++)
          oacc[d][r] = oacc[d][r] * er0[r] + osm[s2][qg * 4 + r][d * 16 + rr] * er1[r];
    }
    float lb[4];
#pragma unroll
    for (int r = 0; r < 4; r++) lb[r] = __shfl(l_r, qg * 4 + r);
    u16* obp = o + (size_t)(b * T_ + q0) * C_ + h * 64;
#pragma unroll
    for (int d = 0; d < 4; d++)
#pragma unroll
      for (int r = 0; r < 4; r++) {
        int row = qg * 4 + r;
        obp[(size_t)row * C_ + d * 16 + rr] = f2bf(oacc[d][r] / lb[r]);
      }
  }
}

extern "C" void kernel_launch(void* const* d_in, const int* in_sizes, int n_in,
                              void* d_out, int out_size, void* d_ws, size_t ws_size,
                              hipStream_t stream) {
  (void)in_sizes; (void)n_in; (void)out_size; (void)ws_size;
  const int*   xidx = (const int*)d_in[0];
  const float* tok  = (const float*)d_in[1];
  const float* pos  = (const float*)d_in[2];
  const float* ln1g = (const float*)d_in[3];
  const float* ln1b = (const float*)d_in[4];
  const float* wq   = (const float*)d_in[5];
  const float* wk   = (const float*)d_in[6];
  const float* wv   = (const float*)d_in[7];
  const float* wo   = (const float*)d_in[8];
  const float* bo   = (const float*)d_in[9];
  const float* ln2g = (const float*)d_in[10];
  const float* ln2b = (const float*)d_in[11];
  const float* w1   = (const float*)d_in[12];
  const float* b1   = (const float*)d_in[13];
  const float* w2   = (const float*)d_in[14];
  const float* b2   = (const float*)d_in[15];
  const float* lnfg = (const float*)d_in[16];
  const float* lnfb = (const float*)d_in[17];
  const float* wp   = (const float*)d_in[18];
  const float* bp   = (const float*)d_in[19];

  char* ws = (char*)d_ws;
  size_t off = 0;
  auto alloc = [&](size_t bytes) { char* p = ws + off; off += (bytes + 255) & ~(size_t)255; return p; };
  u16* wqkvT = (u16*)alloc((size_t)L_ * 3 * C_ * C_ * 2);   // [l][3C][C]
  u16* woT = (u16*)alloc((size_t)L_ * C_ * C_ * 2);
  u16* w1T = (u16*)alloc((size_t)L_ * C_ * F_ * 2);
  u16* w2T = (u16*)alloc((size_t)L_ * C_ * F_ * 2);
  u16* wpT = (u16*)alloc((size_t)C_ * V_ * 2);
  float* x = (float*)alloc((size_t)M_ * C_ * 4);
  float* ps0 = (float*)alloc((size_t)2 * M_ * C_ * 4);   // split-K partial slabs (kz 0/1)
  u16* hb   = (u16*)alloc((size_t)M_ * C_ * 2);
  u16* qkvb = (u16*)alloc((size_t)M_ * C3_ * 2);
  u16* vtb  = (u16*)alloc((size_t)M_ * C_ * 2);
  u16* aob  = (u16*)alloc((size_t)M_ * C_ * 2);
  u16* mb   = (u16*)alloc((size_t)M_ * F_ * 2);
  float* ps1 = ps0 + (size_t)M_ * C_;

  dim3 blk(256);
  size_t CC = (size_t)C_ * C_, CF = (size_t)C_ * F_;
  transpose4_qkvo<<<dim3(C_ / 32, C_ / 32, L_ * 4), blk, 0, stream>>>(
      wq, wk, wv, wo, wqkvT, woT);
  transpose_f32_bf16<<<dim3(F_ / 32, C_ / 32, L_), blk, 0, stream>>>(w1, w1T, C_, F_, CF, CF);
  transpose_f32_bf16<<<dim3(C_ / 32, F_ / 32, L_), blk, 0, stream>>>(w2, w2T, F_, C_, CF, CF);
  transpose_f32_bf16<<<dim3(V_ / 32, C_ / 32, 1), blk, 0, stream>>>(wp, wpT, C_, V_, 0, 0);
  embed_ln<<<M_, blk, 0, stream>>>(xidx, tok, pos, ln1g, ln1b, x, hb);

  for (int l = 0; l < L_; ++l) {
    size_t wOff = (size_t)l * 3 * CC;
    size_t oOff = (size_t)l * CC;
    size_t fOff = (size_t)l * CF;
    gemm3<256, 128, 128, 2, 2, 0, 0, 3, 1><<<dim3(M_ / 128, C3_ / 128), 256, 0, stream>>>(
        hb, wqkvT + wOff, nullptr, qkvb, nullptr, vtb, C3_, C_);
    attn_kernel<<<B_ * H_ * (T_ / 16), dim3(256), 0, stream>>>(qkvb, vtb, aob);
    gemm3<256, 128, 128, 2, 2, 1, 0, 4, 2><<<dim3(M_ / 128, C_ / 128, 2), 256, 0, stream>>>(
        aob, woT + oOff, bo + l * C_, nullptr, ps0, nullptr, C_, C_);
    ln_sum<<<M_, blk, 0, stream>>>(x, ps0, ps1, ln2g + l * C_, ln2b + l * C_, hb);
    gemm3<256, 128, 128, 2, 2, 1, 1, 0, 1><<<dim3(M_ / 128, F_ / 128), 256, 0, stream>>>(
        hb, w1T + fOff, b1 + l * F_, mb, nullptr, nullptr, F_, C_);
    gemm3<256, 128, 128, 2, 2, 1, 0, 4, 2><<<dim3(M_ / 128, C_ / 128, 2), 256, 0, stream>>>(
        mb, w2T + fOff, b2 + l * C_, nullptr, ps0, nullptr, C_, F_);
    if (l + 1 < L_)
      ln_sum<<<M_, blk, 0, stream>>>(x, ps0, ps1, ln1g + (l + 1) * C_, ln1b + (l + 1) * C_, hb);
  }
  ln_sum<<<M_, blk, 0, stream>>>(x, ps0, ps1, lnfg, lnfb, hb);
  gemm8<<<dim3(M_ / 256, V_ / 256), 512, 0, stream>>>(
      hb, wpT, bp, (float*)d_out, V_, C_);
}

// Round 17
// 996.243 us; speedup vs baseline: 1.0668x; 1.0078x over previous
//
#include <hip/hip_runtime.h>
#include <stdint.h>

#define DEV __device__ __forceinline__

typedef unsigned short u16;
typedef __attribute__((ext_vector_type(8))) short short8;
typedef __attribute__((ext_vector_type(4))) float floatx4;

#define B_ 2
#define T_ 1024
#define C_ 768
#define H_ 12
#define L_ 6
#define V_ 32000
#define F_ 3072
#define M_ 2048   // B*T
#define C3_ 2304  // 3*C (packed qkv)

#define VMW(n) asm volatile("s_waitcnt vmcnt(" #n ")" ::: "memory")
#define LGKM0 asm volatile("s_waitcnt lgkmcnt(0)" ::: "memory")
#define SBAR __builtin_amdgcn_s_barrier()
#define SCHED0 __builtin_amdgcn_sched_barrier(0)

DEV u16 f2bf(float f) {
  unsigned int u; __builtin_memcpy(&u, &f, 4);
  u += 0x7FFFu + ((u >> 16) & 1u);   // round-to-nearest-even
  return (u16)(u >> 16);
}

// async global->LDS, 16B per lane. LDS ptr wave-uniform; HW adds lane*16.
DEV void gload16(const void* g, void* l) {
  __builtin_amdgcn_global_load_lds(
      (__attribute__((address_space(1))) void*)(uintptr_t)g,
      (__attribute__((address_space(3))) void*)(unsigned int)(uintptr_t)l,
      16, 0, 0);
}

// bijective XCD swizzle (m204)
DEV int xcd_swz(int flat, int nwg) {
  int q = nwg >> 3, r = nwg & 7;
  int xcd = flat & 7, sid = flat >> 3;
  return (xcd < r ? xcd * (q + 1) : r * (q + 1) + (xcd - r) * q) + sid;
}

// ---------------- transpose + f32->bf16 convert: src[z][R][Cc] -> dst[Cc][R] ----------------
__global__ __launch_bounds__(256) void transpose_f32_bf16(
    const float* __restrict__ src, u16* __restrict__ dst, int R, int Cc,
    size_t src_z, size_t dst_z) {
  __shared__ float tile[32][33];
  const float* s = src + (size_t)blockIdx.z * src_z;
  u16* d = dst + (size_t)blockIdx.z * dst_z;
  int c0 = blockIdx.x * 32, r0 = blockIdx.y * 32;
  int tx = threadIdx.x & 31, ty = threadIdx.x >> 5;
#pragma unroll
  for (int i = 0; i < 4; i++)
    tile[ty + 8 * i][tx] = s[(size_t)(r0 + ty + 8 * i) * Cc + (c0 + tx)];
  __syncthreads();
#pragma unroll
  for (int i = 0; i < 4; i++)
    d[(size_t)(c0 + ty + 8 * i) * R + (r0 + tx)] = f2bf(tile[tx][ty + 8 * i]);
}

// ---------------- batched CxC transpose for wq/wk/wv/wo (z = l*4 + wsel) ----------------
__global__ __launch_bounds__(256) void transpose4_qkvo(
    const float* __restrict__ wq, const float* __restrict__ wk,
    const float* __restrict__ wv, const float* __restrict__ wo,
    u16* __restrict__ wqkvT, u16* __restrict__ woT) {
  __shared__ float tile[32][33];
  int z = blockIdx.z;
  int l = z >> 2, wsel = z & 3;
  size_t CC = (size_t)C_ * C_;
  const float* s = (wsel == 0 ? wq : wsel == 1 ? wk : wsel == 2 ? wv : wo) + (size_t)l * CC;
  u16* d = (wsel < 3) ? (wqkvT + (size_t)l * 3 * CC + (size_t)wsel * CC)
                      : (woT + (size_t)l * CC);
  int c0 = blockIdx.x * 32, r0 = blockIdx.y * 32;
  int tx = threadIdx.x & 31, ty = threadIdx.x >> 5;
#pragma unroll
  for (int i = 0; i < 4; i++)
    tile[ty + 8 * i][tx] = s[(size_t)(r0 + ty + 8 * i) * C_ + (c0 + tx)];
  __syncthreads();
#pragma unroll
  for (int i = 0; i < 4; i++)
    d[(size_t)(c0 + ty + 8 * i) * C_ + (r0 + tx)] = f2bf(tile[tx][ty + 8 * i]);
}

// ---------------- fused embedding + layer-0 LN1: writes x (f32) and hb (bf16) ----------------
__global__ __launch_bounds__(256) void embed_ln(
    const int* __restrict__ idx, const float* __restrict__ tok,
    const float* __restrict__ pos, const float* __restrict__ g,
    const float* __restrict__ b, float* __restrict__ x, u16* __restrict__ out) {
  int row = blockIdx.x;
  int t = row & (T_ - 1);
  int tk = idx[row];
  const float* tp = tok + (size_t)tk * C_;
  const float* pp = pos + (size_t)t * C_;
  float* xp = x + (size_t)row * C_;
  int tid = threadIdx.x;
  float v0 = tp[tid] + pp[tid];
  float v1 = tp[tid + 256] + pp[tid + 256];
  float v2 = tp[tid + 512] + pp[tid + 512];
  xp[tid] = v0; xp[tid + 256] = v1; xp[tid + 512] = v2;
  float s = v0 + v1 + v2;
  float ss = v0 * v0 + v1 * v1 + v2 * v2;
#pragma unroll
  for (int o = 32; o > 0; o >>= 1) { s += __shfl_down(s, o); ss += __shfl_down(ss, o); }
  __shared__ float red[8];
  int wid = tid >> 6;
  if ((tid & 63) == 0) { red[wid] = s; red[4 + wid] = ss; }
  __syncthreads();
  float tot = red[0] + red[1] + red[2] + red[3];
  float tss = red[4] + red[5] + red[6] + red[7];
  float mean = tot * (1.f / C_);
  float var = tss * (1.f / C_) - mean * mean;
  float rstd = rsqrtf(var + 1e-5f);
  u16* op = out + (size_t)row * C_;
  op[tid]       = f2bf((v0 - mean) * rstd * g[tid]       + b[tid]);
  op[tid + 256] = f2bf((v1 - mean) * rstd * g[tid + 256] + b[tid + 256]);
  op[tid + 512] = f2bf((v2 - mean) * rstd * g[tid + 512] + b[tid + 512]);
}

// ---------------- fused residual-sum + layernorm: x += p0 + p1; hb = LN(x) ----------------
__global__ __launch_bounds__(256) void ln_sum(
    float* __restrict__ x, const float* __restrict__ p0, const float* __restrict__ p1,
    const float* __restrict__ g, const float* __restrict__ b, u16* __restrict__ out) {
  int row = blockIdx.x;
  int tid = threadIdx.x;
  size_t base = (size_t)row * C_;
  float* xp = x + base;
  const float* q0 = p0 + base;
  const float* q1 = p1 + base;
  float v0 = xp[tid]       + q0[tid]       + q1[tid];
  float v1 = xp[tid + 256] + q0[tid + 256] + q1[tid + 256];
  float v2 = xp[tid + 512] + q0[tid + 512] + q1[tid + 512];
  xp[tid] = v0; xp[tid + 256] = v1; xp[tid + 512] = v2;
  float s = v0 + v1 + v2;
  float ss = v0 * v0 + v1 * v1 + v2 * v2;
#pragma unroll
  for (int o = 32; o > 0; o >>= 1) { s += __shfl_down(s, o); ss += __shfl_down(ss, o); }
  __shared__ float red[8];
  int wid = tid >> 6;
  if ((tid & 63) == 0) { red[wid] = s; red[4 + wid] = ss; }
  __syncthreads();
  float tot = red[0] + red[1] + red[2] + red[3];
  float tss = red[4] + red[5] + red[6] + red[7];
  float mean = tot * (1.f / C_);
  float var = tss * (1.f / C_) - mean * mean;
  float rstd = rsqrtf(var + 1e-5f);
  u16* op = out + (size_t)row * C_;
  op[tid]       = f2bf((v0 - mean) * rstd * g[tid]       + b[tid]);
  op[tid + 256] = f2bf((v1 - mean) * rstd * g[tid + 256] + b[tid + 256]);
  op[tid + 512] = f2bf((v2 - mean) * rstd * g[tid + 512] + b[tid + 512]);
}

// ---------------- GEMM (layer ops): BK=32, 3-deep ring + counted vmcnt (R5-proven) ----------------
// OUTMODE: 0 = bf16 out, 2 = f32 out, 3 = qkv mode (V^T fused),
//          4 = f32 partial slab (fout + kz*M_*N), no atomics; bias on kz==0
template <int THREADS, int BM, int BN, int WM, int WN, int BIAS, int RELU, int OUTMODE, int SPLITK>
__global__ __launch_bounds__(THREADS) void gemm3(
    const u16* __restrict__ A, const u16* __restrict__ BT,
    const float* __restrict__ bias,
    u16* __restrict__ ob, float* __restrict__ fout, u16* __restrict__ vt,
    int N, int K) {
  constexpr int ALOADS = (BM * 64) / (THREADS * 16);
  constexpr int BLOADS = (BN * 64) / (THREADS * 16);
  constexpr int LDS_L = ALOADS + BLOADS;
  constexpr int MF = BM / (WM * 16);
  constexpr int NF = BN / (WN * 16);
  __shared__ __align__(16) u16 As[3][BM * 32];
  __shared__ __align__(16) u16 Bs[3][BN * 32];

  int tid = threadIdx.x;
  int lane = tid & 63, w = tid >> 6;
  int wm = w / WN, wn = w % WN;
  int rr = lane & 15, qg = lane >> 4;

  int gx = gridDim.x;
  int nwg = gx * gridDim.y;
  int flat = blockIdx.y * gx + blockIdx.x;
  int wg = xcd_swz(flat, nwg);
  int m0 = (wg % gx) * BM, n0 = (wg / gx) * BN;

  int kz = SPLITK > 1 ? blockIdx.z : 0;
  int Keff = SPLITK > 1 ? (K / SPLITK) : K;
  int kbase = kz * Keff;

  const u16* Aps[ALOADS];
  const u16* Bps[BLOADS];
#pragma unroll
  for (int i = 0; i < ALOADS; i++) {
    int idx = i * THREADS + tid;
    int row = idx >> 2;
    int chunk = (idx & 3) ^ ((row >> 1) & 3);
    Aps[i] = A + (size_t)(m0 + row) * K + chunk * 8 + kbase;
  }
#pragma unroll
  for (int i = 0; i < BLOADS; i++) {
    int idx = i * THREADS + tid;
    int row = idx >> 2;
    int chunk = (idx & 3) ^ ((row >> 1) & 3);
    Bps[i] = BT + (size_t)(n0 + row) * K + chunk * 8 + kbase;
  }

  auto stage = [&](int sl, int kk) {
#pragma unroll
    for (int i = 0; i < ALOADS; i++)
      gload16(Aps[i] + kk, (char*)As + (size_t)sl * BM * 64 + i * THREADS * 16 + w * 1024);
#pragma unroll
    for (int i = 0; i < BLOADS; i++)
      gload16(Bps[i] + kk, (char*)Bs + (size_t)sl * BN * 64 + i * THREADS * 16 + w * 1024);
  };

  floatx4 zero = {0.f, 0.f, 0.f, 0.f};
  floatx4 acc[MF][NF];
#pragma unroll
  for (int i = 0; i < MF; i++)
#pragma unroll
    for (int j = 0; j < NF; j++) acc[i][j] = zero;

  int NT = Keff >> 5;
  stage(0, 0);
  stage(1, 32);
  if constexpr (LDS_L == 2) VMW(2);
  else if constexpr (LDS_L == 3) VMW(3);
  else if constexpr (LDS_L == 4) VMW(4);
  else VMW(6);
  SBAR;
  SCHED0;

  int sqA = (qg ^ ((rr >> 1) & 3)) << 4;

  for (int t = 0; t < NT; ++t) {
    int sl = t % 3;
    if (t + 2 < NT) stage((t + 2) % 3, (t + 2) << 5);
    SCHED0;
    const char* Ab = (const char*)As + (size_t)sl * BM * 64;
    const char* Bb = (const char*)Bs + (size_t)sl * BN * 64;
    short8 af[MF], bf[NF];
#pragma unroll
    for (int i = 0; i < MF; i++)
      af[i] = *(const short8*)(Ab + ((wm * (BM / WM) + i * 16 + rr) << 6) + sqA);
#pragma unroll
    for (int j = 0; j < NF; j++)
      bf[j] = *(const short8*)(Bb + ((wn * (BN / WN) + j * 16 + rr) << 6) + sqA);
    __builtin_amdgcn_s_setprio(1);
#pragma unroll
    for (int i = 0; i < MF; i++)
#pragma unroll
      for (int j = 0; j < NF; j++)
        acc[i][j] = __builtin_amdgcn_mfma_f32_16x16x32_bf16(af[i], bf[j], acc[i][j], 0, 0, 0);
    __builtin_amdgcn_s_setprio(0);
    if (t < NT - 2) {
      if constexpr (LDS_L == 2) VMW(2);
      else if constexpr (LDS_L == 3) VMW(3);
      else if constexpr (LDS_L == 4) VMW(4);
      else VMW(6);
    } else if (t == NT - 2) VMW(0);
    if (t < NT - 1) { SBAR; SCHED0; }
  }

  int cb = n0 + wn * (BN / WN);
  int rb = m0 + wm * (BM / WM);
  bool isv = (OUTMODE == 3) && (n0 >= 1536);
  float* fo = fout;
  if (OUTMODE == 4) fo = fout + (size_t)kz * M_ * N;
#pragma unroll
  for (int i = 0; i < MF; i++) {
#pragma unroll
    for (int j = 0; j < NF; j++) {
      int col = cb + j * 16 + rr;
      float bv = 0.f;
      if (BIAS && kz == 0) bv = bias[col];
      float vals[4];
#pragma unroll
      for (int r = 0; r < 4; r++) {
        float val = acc[i][j][r] + bv;
        if (RELU) val = fmaxf(val, 0.f);
        vals[r] = val;
      }
      int row0 = rb + i * 16 + qg * 4;
      if (isv) {
        int colv = col - 1536;
        int bb = row0 >> 10, t0 = row0 & (T_ - 1);
        uint2 pk;
        pk.x = (unsigned int)f2bf(vals[0]) | ((unsigned int)f2bf(vals[1]) << 16);
        pk.y = (unsigned int)f2bf(vals[2]) | ((unsigned int)f2bf(vals[3]) << 16);
        *(uint2*)&vt[((size_t)bb * C_ + colv) * T_ + t0] = pk;
      } else {
#pragma unroll
        for (int r = 0; r < 4; r++) {
          size_t o = (size_t)(row0 + r) * N + col;
          if (OUTMODE == 0 || OUTMODE == 3) ob[o] = f2bf(vals[r]);
          else fo[o] = vals[r];
        }
      }
    }
  }
}

// ---------------- 256x256 logits GEMM: m201-style 8-phase, plain scalar stores (converged) ----
__global__ __launch_bounds__(512) void gemm8(
    const u16* __restrict__ A, const u16* __restrict__ BT,
    const float* __restrict__ bias, float* __restrict__ fout, int N, int K) {
  __shared__ __align__(16) u16 As[2][2][128 * 64];
  __shared__ __align__(16) u16 Bs[2][2][128 * 64];
  int tid = threadIdx.x;
  int lane = tid & 63, w = tid >> 6;
  int wr = w >> 2, wc = w & 3;
  int rr = lane & 15, qg = lane >> 4;

  int gx = gridDim.x;
  int nwg = gx * gridDim.y;
  int flat = blockIdx.y * gx + blockIdx.x;
  int wg = xcd_swz(flat, nwg);
  int m0 = (wg % gx) * 256, n0 = (wg / gx) * 256;

  int la = tid >> 3;
  int sa = (((tid & 7) ^ (la & 7)) << 3);
  const u16* Ap0 = A + (size_t)(m0 + la) * K + sa;
  const u16* Ap1 = A + (size_t)(m0 + 128 + la) * K + sa;
  int lb0 = la, lb1 = 64 + la;
  const u16* Bp0 = BT + (size_t)(n0 + (lb0 >> 5) * 64 + (lb0 & 31)) * K + sa;
  const u16* Bp1 = BT + (size_t)(n0 + (lb1 >> 5) * 64 + (lb1 & 31)) * K + sa;

  auto stA = [&](int buf, int mh, int kt) {
    size_t off = (size_t)mh * 64 * K + kt * 64;
    gload16(Ap0 + off, (char*)&As[buf][mh][0] + w * 1024);
    gload16(Ap1 + off, (char*)&As[buf][mh][0] + 8192 + w * 1024);
  };
  auto stB = [&](int buf, int nh, int kt) {
    size_t off = (size_t)nh * 32 * K + kt * 64;
    gload16(Bp0 + off, (char*)&Bs[buf][nh][0] + w * 1024);
    gload16(Bp1 + off, (char*)&Bs[buf][nh][0] + 8192 + w * 1024);
  };
  auto stageOrd = [&](int buf, int h, int kt) {
    if (h == 0) stA(buf, 0, kt);
    else if (h == 1) stB(buf, 0, kt);
    else if (h == 2) stB(buf, 1, kt);
    else stA(buf, 1, kt);
  };

  floatx4 zero = {0.f, 0.f, 0.f, 0.f};
  floatx4 acc[8][4];
#pragma unroll
  for (int i = 0; i < 8; i++)
#pragma unroll
    for (int j = 0; j < 4; j++) acc[i][j] = zero;

  short8 a[2][4], b[2][2];
  int NKT = K >> 6;
  int NIT = NKT >> 1;

  stageOrd(0, 0, 0); stageOrd(0, 1, 0); stageOrd(0, 2, 0); stageOrd(0, 3, 0);
  VMW(4);
  SBAR;
  SCHED0;

  for (int it = 0; it < NIT; ++it) {
    int kt2 = it * 2;
    bool last = (it == NIT - 1);
#pragma unroll
    for (int p = 0; p < 8; ++p) {
      const int d = p >> 2;
      const int q = p & 3;
      const int mh = q >> 1, nh = q & 1;
      const char* Abp = (const char*)&As[d][mh][0];
      const char* Bbp = (const char*)&Bs[d][nh][0];
      if (q == 0 || q == 2) {
#pragma unroll
        for (int kk = 0; kk < 2; kk++)
#pragma unroll
          for (int i = 0; i < 4; i++) {
            int l = wr * 64 + i * 16 + rr;
            a[kk][i] = *(const short8*)(Abp + l * 128 + ((((kk << 2) + qg) ^ (rr & 7)) << 4));
          }
      }
#pragma unroll
      for (int kk = 0; kk < 2; kk++)
#pragma unroll
        for (int j = 0; j < 2; j++) {
          int l = wc * 32 + j * 16 + rr;
          b[kk][j] = *(const short8*)(Bbp + l * 128 + ((((kk << 2) + qg) ^ (rr & 7)) << 4));
        }
      if (p < 4) stageOrd(1, q, kt2 + 1);
      else if (!last) stageOrd(0, q, kt2 + 2);
      SCHED0;
      SBAR;
      LGKM0;
      SCHED0;
      __builtin_amdgcn_s_setprio(1);
#pragma unroll
      for (int kk = 0; kk < 2; kk++)
#pragma unroll
        for (int i = 0; i < 4; i++)
#pragma unroll
          for (int j = 0; j < 2; j++)
            acc[mh * 4 + i][nh * 2 + j] = __builtin_amdgcn_mfma_f32_16x16x32_bf16(
                a[kk][i], b[kk][j], acc[mh * 4 + i][nh * 2 + j], 0, 0, 0);
      __builtin_amdgcn_s_setprio(0);
      if (!last || p < 4) VMW(4);
      else if (p == 4) VMW(2);
      else if (p == 5) VMW(0);
      SBAR;
      SCHED0;
    }
  }

  int rbase = m0 + wr * 128;
  int cbase = n0 + wc * 64;
#pragma unroll
  for (int fi = 0; fi < 8; fi++) {
    int row0 = rbase + (fi >> 2) * 64 + (fi & 3) * 16 + qg * 4;
#pragma unroll
    for (int fj = 0; fj < 4; fj++) {
      int col = cbase + (fj >> 1) * 32 + (fj & 1) * 16 + rr;
      float bv = bias[col];
#pragma unroll
      for (int r = 0; r < 4; r++)
        fout[(size_t)(row0 + r) * N + col] = acc[fi][fj][r] + bv;
    }
  }
}

// ---------------- fused causal attention: 4-wave KV-split + online-softmax merge ----------------
__global__ __launch_bounds__(256) void attn_kernel(
    const u16* __restrict__ qkv, const u16* __restrict__ vt, u16* __restrict__ o) {
  __shared__ __align__(16) u16 P_s[4][16 * 48];
  __shared__ float mls[3][2][16];
  __shared__ float osm[3][16][64];
  int nwg = gridDim.x;
  int wg = xcd_swz(blockIdx.x, nwg);
  int qt = wg & 63;
  int h = (wg >> 6) % H_;
  int b = wg / (64 * H_);
  int q0 = qt << 4;
  int tid = threadIdx.x;
  int ws = tid >> 6;
  int lane = tid & 63;
  int rr = lane & 15, qg = lane >> 4, kq = qg << 3;

  const u16* qb = qkv + (size_t)(b * T_ + q0 + rr) * C3_ + h * 64;
  short8 qf0 = *(const short8*)(qb + kq);
  short8 qf1 = *(const short8*)(qb + 32 + kq);

  float m_r = -1e30f, l_r = 0.f;
  floatx4 zero = {0.f, 0.f, 0.f, 0.f};
  floatx4 oacc[4];
#pragma unroll
  for (int d = 0; d < 4; d++) oacc[d] = zero;

  const u16* kbase = qkv + (size_t)(b * T_) * C3_ + 768 + h * 64;
  const u16* vbase = vt + (size_t)(b * C_ + h * 64) * T_;

  for (int kt0 = ws * 32; kt0 <= q0 + 15; kt0 += 128) {
    floatx4 s[2];
#pragma unroll
    for (int c = 0; c < 2; c++) {
      const u16* kb = kbase + (size_t)(kt0 + c * 16 + rr) * C3_;
      short8 kf0 = *(const short8*)(kb + kq);
      short8 kf1 = *(const short8*)(kb + 32 + kq);
      floatx4 z = zero;
      z = __builtin_amdgcn_mfma_f32_16x16x32_bf16(kf0, qf0, z, 0, 0, 0);
      z = __builtin_amdgcn_mfma_f32_16x16x32_bf16(kf1, qf1, z, 0, 0, 0);
      s[c] = z;
    }
    int qpos = q0 + rr;
    float p[2][4];
    float mx = -1e30f;
#pragma unroll
    for (int c = 0; c < 2; c++)
#pragma unroll
      for (int r = 0; r < 4; r++) {
        int kpos = kt0 + c * 16 + qg * 4 + r;
        float val = s[c][r] * 0.125f;
        val = (kpos <= qpos) ? val : -1e30f;
        p[c][r] = val;
        mx = fmaxf(mx, val);
      }
    mx = fmaxf(mx, __shfl_xor(mx, 16));
    mx = fmaxf(mx, __shfl_xor(mx, 32));
    float mn = fmaxf(m_r, mx);
    float escL = exp2f((m_r - mn) * 1.44269504f);
    m_r = mn;
    float ps = 0.f;
#pragma unroll
    for (int c = 0; c < 2; c++)
#pragma unroll
      for (int r = 0; r < 4; r++) {
        float pv = exp2f((p[c][r] - mn) * 1.44269504f);
        p[c][r] = pv;
        ps += pv;
      }
    ps += __shfl_xor(ps, 16);
    ps += __shfl_xor(ps, 32);
    l_r = l_r * escL + ps;
#pragma unroll
    for (int c = 0; c < 2; c++) {
      unsigned int u0 = (unsigned int)f2bf(p[c][0]) | ((unsigned int)f2bf(p[c][1]) << 16);
      unsigned int u1 = (unsigned int)f2bf(p[c][2]) | ((unsigned int)f2bf(p[c][3]) << 16);
      uint2 pk; pk.x = u0; pk.y = u1;
      *(uint2*)&P_s[ws][rr * 48 + c * 16 + qg * 4] = pk;
    }
    float er[4];
#pragma unroll
    for (int r = 0; r < 4; r++) er[r] = __shfl(escL, qg * 4 + r);
#pragma unroll
    for (int d = 0; d < 4; d++)
#pragma unroll
      for (int r = 0; r < 4; r++) oacc[d][r] *= er[r];
    short8 pa = *(const short8*)&P_s[ws][rr * 48 + kq];
#pragma unroll
    for (int d = 0; d < 4; d++) {
      short8 vf = *(const short8*)(vbase + (size_t)(d * 16 + rr) * T_ + kt0 + kq);
      oacc[d] = __builtin_amdgcn_mfma_f32_16x16x32_bf16(pa, vf, oacc[d], 0, 0, 0);
    }
  }

  // partials -> LDS (waves 1..3); merge in wave 0
  if (ws != 0) {
    if (qg == 0) { mls[ws - 1][0][rr] = m_r; mls[ws - 1][1][rr] = l_r; }
#pragma unroll
    for (int d = 0; d < 4; d++)
#pragma unroll
      for (int r = 0; r < 4; r++)
        osm[ws - 1][qg * 4 + r][d * 16 + rr] = oacc[d][r];
  }
  __syncthreads();
  if (ws == 0) {
#pragma unroll
    for (int s2 = 0; s2 < 3; s2++) {
      float mw = mls[s2][0][rr];
      float lw = mls[s2][1][rr];
      float mn = fmaxf(m_r, mw);
      float e0 = exp2f((m_r - mn) * 1.44269504f);
      float e1 = exp2f((mw - mn) * 1.44269504f);
      m_r = mn;
      l_r = l_r * e0 + lw * e1;
      float er0[4], er1[4];
#pragma unroll
      for (int r = 0; r < 4; r++) {
        er0[r] = __shfl(e0, qg * 4 + r);
        er1[r] = __shfl(e1, qg * 4 + r);
      }
#pragma unroll
      for (int d = 0; d < 4; d++)
#pragma unroll
        for (int r = 0; r < 4; r++)
          oacc[d][r] = oacc[d][r] * er0[r] + osm[s2][qg * 4 + r][d * 16 + rr] * er1[r];
    }
    float lb[4];
#pragma unroll
    for (int r = 0; r < 4; r++) lb[r] = __shfl(l_r, qg * 4 + r);
    u16* obp = o + (size_t)(b * T_ + q0) * C_ + h * 64;
#pragma unroll
    for (int d = 0; d < 4; d++)
#pragma unroll
      for (int r = 0; r < 4; r++) {
        int row = qg * 4 + r;
        obp[(size_t)row * C_ + d * 16 + rr] = f2bf(oacc[d][r] / lb[r]);
      }
  }
}

extern "C" void kernel_launch(void* const* d_in, const int* in_sizes, int n_in,
                              void* d_out, int out_size, void* d_ws, size_t ws_size,
                              hipStream_t stream) {
  (void)in_sizes; (void)n_in; (void)out_size; (void)ws_size;
  const int*   xidx = (const int*)d_in[0];
  const float* tok  = (const float*)d_in[1];
  const float* pos  = (const float*)d_in[2];
  const float* ln1g = (const float*)d_in[3];
  const float* ln1b = (const float*)d_in[4];
  const float* wq   = (const float*)d_in[5];
  const float* wk   = (const float*)d_in[6];
  const float* wv   = (const float*)d_in[7];
  const float* wo   = (const float*)d_in[8];
  const float* bo   = (const float*)d_in[9];
  const float* ln2g = (const float*)d_in[10];
  const float* ln2b = (const float*)d_in[11];
  const float* w1   = (const float*)d_in[12];
  const float* b1   = (const float*)d_in[13];
  const float* w2   = (const float*)d_in[14];
  const float* b2   = (const float*)d_in[15];
  const float* lnfg = (const float*)d_in[16];
  const float* lnfb = (const float*)d_in[17];
  const float* wp   = (const float*)d_in[18];
  const float* bp   = (const float*)d_in[19];

  char* ws = (char*)d_ws;
  size_t off = 0;
  auto alloc = [&](size_t bytes) { char* p = ws + off; off += (bytes + 255) & ~(size_t)255; return p; };
  u16* wqkvT = (u16*)alloc((size_t)L_ * 3 * C_ * C_ * 2);   // [l][3C][C]
  u16* woT = (u16*)alloc((size_t)L_ * C_ * C_ * 2);
  u16* w1T = (u16*)alloc((size_t)L_ * C_ * F_ * 2);
  u16* w2T = (u16*)alloc((size_t)L_ * C_ * F_ * 2);
  u16* wpT = (u16*)alloc((size_t)C_ * V_ * 2);
  float* x = (float*)alloc((size_t)M_ * C_ * 4);
  float* ps0 = (float*)alloc((size_t)2 * M_ * C_ * 4);   // split-K partial slabs (kz 0/1)
  u16* hb   = (u16*)alloc((size_t)M_ * C_ * 2);
  u16* qkvb = (u16*)alloc((size_t)M_ * C3_ * 2);
  u16* vtb  = (u16*)alloc((size_t)M_ * C_ * 2);
  u16* aob  = (u16*)alloc((size_t)M_ * C_ * 2);
  u16* mb   = (u16*)alloc((size_t)M_ * F_ * 2);
  float* ps1 = ps0 + (size_t)M_ * C_;

  dim3 blk(256);
  size_t CC = (size_t)C_ * C_, CF = (size_t)C_ * F_;
  transpose4_qkvo<<<dim3(C_ / 32, C_ / 32, L_ * 4), blk, 0, stream>>>(
      wq, wk, wv, wo, wqkvT, woT);
  transpose_f32_bf16<<<dim3(F_ / 32, C_ / 32, L_), blk, 0, stream>>>(w1, w1T, C_, F_, CF, CF);
  transpose_f32_bf16<<<dim3(C_ / 32, F_ / 32, L_), blk, 0, stream>>>(w2, w2T, F_, C_, CF, CF);
  transpose_f32_bf16<<<dim3(V_ / 32, C_ / 32, 1), blk, 0, stream>>>(wp, wpT, C_, V_, 0, 0);
  embed_ln<<<M_, blk, 0, stream>>>(xidx, tok, pos, ln1g, ln1b, x, hb);

  for (int l = 0; l < L_; ++l) {
    size_t wOff = (size_t)l * 3 * CC;
    size_t oOff = (size_t)l * CC;
    size_t fOff = (size_t)l * CF;
    gemm3<256, 128, 64, 2, 2, 0, 0, 3, 1><<<dim3(M_ / 128, C3_ / 64), 256, 0, stream>>>(
        hb, wqkvT + wOff, nullptr, qkvb, nullptr, vtb, C3_, C_);
    attn_kernel<<<B_ * H_ * (T_ / 16), dim3(256), 0, stream>>>(qkvb, vtb, aob);
    gemm3<256, 128, 64, 2, 2, 1, 0, 4, 2><<<dim3(M_ / 128, C_ / 64, 2), 256, 0, stream>>>(
        aob, woT + oOff, bo + l * C_, nullptr, ps0, nullptr, C_, C_);
    ln_sum<<<M_, blk, 0, stream>>>(x, ps0, ps1, ln2g + l * C_, ln2b + l * C_, hb);
    gemm3<256, 128, 64, 2, 2, 1, 1, 0, 1><<<dim3(M_ / 128, F_ / 64), 256, 0, stream>>>(
        hb, w1T + fOff, b1 + l * F_, mb, nullptr, nullptr, F_, C_);
    gemm3<256, 128, 64, 2, 2, 1, 0, 4, 2><<<dim3(M_ / 128, C_ / 64, 2), 256, 0, stream>>>(
        mb, w2T + fOff, b2 + l * C_, nullptr, ps0, nullptr, C_, F_);
    if (l + 1 < L_)
      ln_sum<<<M_, blk, 0, stream>>>(x, ps0, ps1, ln1g + (l + 1) * C_, ln1b + (l + 1) * C_, hb);
  }
  ln_sum<<<M_, blk, 0, stream>>>(x, ps0, ps1, lnfg, lnfb, hb);
  gemm8<<<dim3(M_ / 256, V_ / 256), 512, 0, stream>>>(
      hb, wpT, bp, (float*)d_out, V_, C_);
}

// Round 18
// 996.192 us; speedup vs baseline: 1.0668x; 1.0001x over previous
//
#include <hip/hip_runtime.h>
#include <stdint.h>

#define DEV __device__ __forceinline__

typedef unsigned short u16;
typedef __attribute__((ext_vector_type(8))) short short8;
typedef __attribute__((ext_vector_type(4))) float floatx4;

#define B_ 2
#define T_ 1024
#define C_ 768
#define H_ 12
#define L_ 6
#define V_ 32000
#define F_ 3072
#define M_ 2048   // B*T
#define C3_ 2304  // 3*C (packed qkv)

#define VMW(n) asm volatile("s_waitcnt vmcnt(" #n ")" ::: "memory")
#define LGKM0 asm volatile("s_waitcnt lgkmcnt(0)" ::: "memory")
#define SBAR __builtin_amdgcn_s_barrier()
#define SCHED0 __builtin_amdgcn_sched_barrier(0)

DEV u16 f2bf(float f) {
  unsigned int u; __builtin_memcpy(&u, &f, 4);
  u += 0x7FFFu + ((u >> 16) & 1u);   // round-to-nearest-even
  return (u16)(u >> 16);
}

// async global->LDS, 16B per lane. LDS ptr wave-uniform; HW adds lane*16.
DEV void gload16(const void* g, void* l) {
  __builtin_amdgcn_global_load_lds(
      (__attribute__((address_space(1))) void*)(uintptr_t)g,
      (__attribute__((address_space(3))) void*)(unsigned int)(uintptr_t)l,
      16, 0, 0);
}

// bijective XCD swizzle (m204)
DEV int xcd_swz(int flat, int nwg) {
  int q = nwg >> 3, r = nwg & 7;
  int xcd = flat & 7, sid = flat >> 3;
  return (xcd < r ? xcd * (q + 1) : r * (q + 1) + (xcd - r) * q) + sid;
}

// ---------------- transpose + f32->bf16 convert: src[z][R][Cc] -> dst[Cc][R] ----------------
__global__ __launch_bounds__(256) void transpose_f32_bf16(
    const float* __restrict__ src, u16* __restrict__ dst, int R, int Cc,
    size_t src_z, size_t dst_z) {
  __shared__ float tile[32][33];
  const float* s = src + (size_t)blockIdx.z * src_z;
  u16* d = dst + (size_t)blockIdx.z * dst_z;
  int c0 = blockIdx.x * 32, r0 = blockIdx.y * 32;
  int tx = threadIdx.x & 31, ty = threadIdx.x >> 5;
#pragma unroll
  for (int i = 0; i < 4; i++)
    tile[ty + 8 * i][tx] = s[(size_t)(r0 + ty + 8 * i) * Cc + (c0 + tx)];
  __syncthreads();
#pragma unroll
  for (int i = 0; i < 4; i++)
    d[(size_t)(c0 + ty + 8 * i) * R + (r0 + tx)] = f2bf(tile[tx][ty + 8 * i]);
}

// ---------------- batched CxC transpose for wq/wk/wv/wo (z = l*4 + wsel) ----------------
__global__ __launch_bounds__(256) void transpose4_qkvo(
    const float* __restrict__ wq, const float* __restrict__ wk,
    const float* __restrict__ wv, const float* __restrict__ wo,
    u16* __restrict__ wqkvT, u16* __restrict__ woT) {
  __shared__ float tile[32][33];
  int z = blockIdx.z;
  int l = z >> 2, wsel = z & 3;
  size_t CC = (size_t)C_ * C_;
  const float* s = (wsel == 0 ? wq : wsel == 1 ? wk : wsel == 2 ? wv : wo) + (size_t)l * CC;
  u16* d = (wsel < 3) ? (wqkvT + (size_t)l * 3 * CC + (size_t)wsel * CC)
                      : (woT + (size_t)l * CC);
  int c0 = blockIdx.x * 32, r0 = blockIdx.y * 32;
  int tx = threadIdx.x & 31, ty = threadIdx.x >> 5;
#pragma unroll
  for (int i = 0; i < 4; i++)
    tile[ty + 8 * i][tx] = s[(size_t)(r0 + ty + 8 * i) * C_ + (c0 + tx)];
  __syncthreads();
#pragma unroll
  for (int i = 0; i < 4; i++)
    d[(size_t)(c0 + ty + 8 * i) * C_ + (r0 + tx)] = f2bf(tile[tx][ty + 8 * i]);
}

// ---------------- vectorized fused embedding + layer-0 LN1 (1 wave per row) ----------------
__global__ __launch_bounds__(256) void embed_ln(
    const int* __restrict__ idx, const float* __restrict__ tok,
    const float* __restrict__ pos, const float* __restrict__ g,
    const float* __restrict__ b, float* __restrict__ x, u16* __restrict__ out) {
  int row = blockIdx.x * 4 + (threadIdx.x >> 6);
  int lane = threadIdx.x & 63;
  int t = row & (T_ - 1);
  int tk = idx[row];
  size_t base = (size_t)row * C_;
  const float* tp = tok + (size_t)tk * C_;
  const float* pp = pos + (size_t)t * C_;
  floatx4 v[3];
  float s = 0.f, ss = 0.f;
#pragma unroll
  for (int k = 0; k < 3; k++) {
    int c = k * 256 + lane * 4;
    floatx4 a = *(const floatx4*)&tp[c];
    floatx4 q = *(const floatx4*)&pp[c];
#pragma unroll
    for (int j = 0; j < 4; j++) a[j] += q[j];
    v[k] = a;
    *(floatx4*)&x[base + c] = a;
#pragma unroll
    for (int j = 0; j < 4; j++) { s += a[j]; ss += a[j] * a[j]; }
  }
#pragma unroll
  for (int o = 32; o > 0; o >>= 1) { s += __shfl_xor(s, o); ss += __shfl_xor(ss, o); }
  float mean = s * (1.f / C_);
  float rstd = rsqrtf(ss * (1.f / C_) - mean * mean + 1e-5f);
#pragma unroll
  for (int k = 0; k < 3; k++) {
    int c = k * 256 + lane * 4;
    floatx4 gg = *(const floatx4*)&g[c];
    floatx4 bb = *(const floatx4*)&b[c];
    float o0 = (v[k][0] - mean) * rstd * gg[0] + bb[0];
    float o1 = (v[k][1] - mean) * rstd * gg[1] + bb[1];
    float o2 = (v[k][2] - mean) * rstd * gg[2] + bb[2];
    float o3 = (v[k][3] - mean) * rstd * gg[3] + bb[3];
    uint2 pk;
    pk.x = (unsigned int)f2bf(o0) | ((unsigned int)f2bf(o1) << 16);
    pk.y = (unsigned int)f2bf(o2) | ((unsigned int)f2bf(o3) << 16);
    *(uint2*)&out[base + c] = pk;
  }
}

// ---------------- vectorized fused residual-sum + LN: x += p0 + p1; hb = LN(x) ----------------
// 4 rows/block, 1 wave per row, float4 accesses, wave-local shfl reduction (no LDS).
__global__ __launch_bounds__(256) void ln_sum(
    float* __restrict__ x, const float* __restrict__ p0, const float* __restrict__ p1,
    const float* __restrict__ g, const float* __restrict__ b, u16* __restrict__ out) {
  int row = blockIdx.x * 4 + (threadIdx.x >> 6);
  int lane = threadIdx.x & 63;
  size_t base = (size_t)row * C_;
  floatx4 v[3];
  float s = 0.f, ss = 0.f;
#pragma unroll
  for (int k = 0; k < 3; k++) {
    int c = k * 256 + lane * 4;
    floatx4 a = *(const floatx4*)&x[base + c];
    floatx4 q = *(const floatx4*)&p0[base + c];
    floatx4 r = *(const floatx4*)&p1[base + c];
#pragma unroll
    for (int j = 0; j < 4; j++) a[j] += q[j] + r[j];
    v[k] = a;
    *(floatx4*)&x[base + c] = a;
#pragma unroll
    for (int j = 0; j < 4; j++) { s += a[j]; ss += a[j] * a[j]; }
  }
#pragma unroll
  for (int o = 32; o > 0; o >>= 1) { s += __shfl_xor(s, o); ss += __shfl_xor(ss, o); }
  float mean = s * (1.f / C_);
  float rstd = rsqrtf(ss * (1.f / C_) - mean * mean + 1e-5f);
#pragma unroll
  for (int k = 0; k < 3; k++) {
    int c = k * 256 + lane * 4;
    floatx4 gg = *(const floatx4*)&g[c];
    floatx4 bb = *(const floatx4*)&b[c];
    float o0 = (v[k][0] - mean) * rstd * gg[0] + bb[0];
    float o1 = (v[k][1] - mean) * rstd * gg[1] + bb[1];
    float o2 = (v[k][2] - mean) * rstd * gg[2] + bb[2];
    float o3 = (v[k][3] - mean) * rstd * gg[3] + bb[3];
    uint2 pk;
    pk.x = (unsigned int)f2bf(o0) | ((unsigned int)f2bf(o1) << 16);
    pk.y = (unsigned int)f2bf(o2) | ((unsigned int)f2bf(o3) << 16);
    *(uint2*)&out[base + c] = pk;
  }
}

// ---------------- GEMM (layer ops): BK=32, 3-deep ring + counted vmcnt (R5-proven) ----------------
// OUTMODE: 0 = bf16 out, 2 = f32 out, 3 = qkv mode (V^T fused),
//          4 = f32 partial slab (fout + kz*M_*N), no atomics; bias on kz==0
template <int THREADS, int BM, int BN, int WM, int WN, int BIAS, int RELU, int OUTMODE, int SPLITK>
__global__ __launch_bounds__(THREADS) void gemm3(
    const u16* __restrict__ A, const u16* __restrict__ BT,
    const float* __restrict__ bias,
    u16* __restrict__ ob, float* __restrict__ fout, u16* __restrict__ vt,
    int N, int K) {
  constexpr int ALOADS = (BM * 64) / (THREADS * 16);
  constexpr int BLOADS = (BN * 64) / (THREADS * 16);
  constexpr int LDS_L = ALOADS + BLOADS;
  constexpr int MF = BM / (WM * 16);
  constexpr int NF = BN / (WN * 16);
  __shared__ __align__(16) u16 As[3][BM * 32];
  __shared__ __align__(16) u16 Bs[3][BN * 32];

  int tid = threadIdx.x;
  int lane = tid & 63, w = tid >> 6;
  int wm = w / WN, wn = w % WN;
  int rr = lane & 15, qg = lane >> 4;

  int gx = gridDim.x;
  int nwg = gx * gridDim.y;
  int flat = blockIdx.y * gx + blockIdx.x;
  int wg = xcd_swz(flat, nwg);
  int m0 = (wg % gx) * BM, n0 = (wg / gx) * BN;

  int kz = SPLITK > 1 ? blockIdx.z : 0;
  int Keff = SPLITK > 1 ? (K / SPLITK) : K;
  int kbase = kz * Keff;

  const u16* Aps[ALOADS];
  const u16* Bps[BLOADS];
#pragma unroll
  for (int i = 0; i < ALOADS; i++) {
    int idx = i * THREADS + tid;
    int row = idx >> 2;
    int chunk = (idx & 3) ^ ((row >> 1) & 3);
    Aps[i] = A + (size_t)(m0 + row) * K + chunk * 8 + kbase;
  }
#pragma unroll
  for (int i = 0; i < BLOADS; i++) {
    int idx = i * THREADS + tid;
    int row = idx >> 2;
    int chunk = (idx & 3) ^ ((row >> 1) & 3);
    Bps[i] = BT + (size_t)(n0 + row) * K + chunk * 8 + kbase;
  }

  auto stage = [&](int sl, int kk) {
#pragma unroll
    for (int i = 0; i < ALOADS; i++)
      gload16(Aps[i] + kk, (char*)As + (size_t)sl * BM * 64 + i * THREADS * 16 + w * 1024);
#pragma unroll
    for (int i = 0; i < BLOADS; i++)
      gload16(Bps[i] + kk, (char*)Bs + (size_t)sl * BN * 64 + i * THREADS * 16 + w * 1024);
  };

  floatx4 zero = {0.f, 0.f, 0.f, 0.f};
  floatx4 acc[MF][NF];
#pragma unroll
  for (int i = 0; i < MF; i++)
#pragma unroll
    for (int j = 0; j < NF; j++) acc[i][j] = zero;

  int NT = Keff >> 5;
  stage(0, 0);
  stage(1, 32);
  if constexpr (LDS_L == 2) VMW(2);
  else if constexpr (LDS_L == 3) VMW(3);
  else if constexpr (LDS_L == 4) VMW(4);
  else VMW(6);
  SBAR;
  SCHED0;

  int sqA = (qg ^ ((rr >> 1) & 3)) << 4;

  for (int t = 0; t < NT; ++t) {
    int sl = t % 3;
    if (t + 2 < NT) stage((t + 2) % 3, (t + 2) << 5);
    SCHED0;
    const char* Ab = (const char*)As + (size_t)sl * BM * 64;
    const char* Bb = (const char*)Bs + (size_t)sl * BN * 64;
    short8 af[MF], bf[NF];
#pragma unroll
    for (int i = 0; i < MF; i++)
      af[i] = *(const short8*)(Ab + ((wm * (BM / WM) + i * 16 + rr) << 6) + sqA);
#pragma unroll
    for (int j = 0; j < NF; j++)
      bf[j] = *(const short8*)(Bb + ((wn * (BN / WN) + j * 16 + rr) << 6) + sqA);
    __builtin_amdgcn_s_setprio(1);
#pragma unroll
    for (int i = 0; i < MF; i++)
#pragma unroll
      for (int j = 0; j < NF; j++)
        acc[i][j] = __builtin_amdgcn_mfma_f32_16x16x32_bf16(af[i], bf[j], acc[i][j], 0, 0, 0);
    __builtin_amdgcn_s_setprio(0);
    if (t < NT - 2) {
      if constexpr (LDS_L == 2) VMW(2);
      else if constexpr (LDS_L == 3) VMW(3);
      else if constexpr (LDS_L == 4) VMW(4);
      else VMW(6);
    } else if (t == NT - 2) VMW(0);
    if (t < NT - 1) { SBAR; SCHED0; }
  }

  int cb = n0 + wn * (BN / WN);
  int rb = m0 + wm * (BM / WM);
  bool isv = (OUTMODE == 3) && (n0 >= 1536);
  float* fo = fout;
  if (OUTMODE == 4) fo = fout + (size_t)kz * M_ * N;
#pragma unroll
  for (int i = 0; i < MF; i++) {
#pragma unroll
    for (int j = 0; j < NF; j++) {
      int col = cb + j * 16 + rr;
      float bv = 0.f;
      if (BIAS && kz == 0) bv = bias[col];
      float vals[4];
#pragma unroll
      for (int r = 0; r < 4; r++) {
        float val = acc[i][j][r] + bv;
        if (RELU) val = fmaxf(val, 0.f);
        vals[r] = val;
      }
      int row0 = rb + i * 16 + qg * 4;
      if (isv) {
        int colv = col - 1536;
        int bb = row0 >> 10, t0 = row0 & (T_ - 1);
        uint2 pk;
        pk.x = (unsigned int)f2bf(vals[0]) | ((unsigned int)f2bf(vals[1]) << 16);
        pk.y = (unsigned int)f2bf(vals[2]) | ((unsigned int)f2bf(vals[3]) << 16);
        *(uint2*)&vt[((size_t)bb * C_ + colv) * T_ + t0] = pk;
      } else {
#pragma unroll
        for (int r = 0; r < 4; r++) {
          size_t o = (size_t)(row0 + r) * N + col;
          if (OUTMODE == 0 || OUTMODE == 3) ob[o] = f2bf(vals[r]);
          else fo[o] = vals[r];
        }
      }
    }
  }
}

// ---------------- 256x256 logits GEMM: m201-style 8-phase, plain scalar stores (converged) ----
__global__ __launch_bounds__(512) void gemm8(
    const u16* __restrict__ A, const u16* __restrict__ BT,
    const float* __restrict__ bias, float* __restrict__ fout, int N, int K) {
  __shared__ __align__(16) u16 As[2][2][128 * 64];
  __shared__ __align__(16) u16 Bs[2][2][128 * 64];
  int tid = threadIdx.x;
  int lane = tid & 63, w = tid >> 6;
  int wr = w >> 2, wc = w & 3;
  int rr = lane & 15, qg = lane >> 4;

  int gx = gridDim.x;
  int nwg = gx * gridDim.y;
  int flat = blockIdx.y * gx + blockIdx.x;
  int wg = xcd_swz(flat, nwg);
  int m0 = (wg % gx) * 256, n0 = (wg / gx) * 256;

  int la = tid >> 3;
  int sa = (((tid & 7) ^ (la & 7)) << 3);
  const u16* Ap0 = A + (size_t)(m0 + la) * K + sa;
  const u16* Ap1 = A + (size_t)(m0 + 128 + la) * K + sa;
  int lb0 = la, lb1 = 64 + la;
  const u16* Bp0 = BT + (size_t)(n0 + (lb0 >> 5) * 64 + (lb0 & 31)) * K + sa;
  const u16* Bp1 = BT + (size_t)(n0 + (lb1 >> 5) * 64 + (lb1 & 31)) * K + sa;

  auto stA = [&](int buf, int mh, int kt) {
    size_t off = (size_t)mh * 64 * K + kt * 64;
    gload16(Ap0 + off, (char*)&As[buf][mh][0] + w * 1024);
    gload16(Ap1 + off, (char*)&As[buf][mh][0] + 8192 + w * 1024);
  };
  auto stB = [&](int buf, int nh, int kt) {
    size_t off = (size_t)nh * 32 * K + kt * 64;
    gload16(Bp0 + off, (char*)&Bs[buf][nh][0] + w * 1024);
    gload16(Bp1 + off, (char*)&Bs[buf][nh][0] + 8192 + w * 1024);
  };
  auto stageOrd = [&](int buf, int h, int kt) {
    if (h == 0) stA(buf, 0, kt);
    else if (h == 1) stB(buf, 0, kt);
    else if (h == 2) stB(buf, 1, kt);
    else stA(buf, 1, kt);
  };

  floatx4 zero = {0.f, 0.f, 0.f, 0.f};
  floatx4 acc[8][4];
#pragma unroll
  for (int i = 0; i < 8; i++)
#pragma unroll
    for (int j = 0; j < 4; j++) acc[i][j] = zero;

  short8 a[2][4], b[2][2];
  int NKT = K >> 6;
  int NIT = NKT >> 1;

  stageOrd(0, 0, 0); stageOrd(0, 1, 0); stageOrd(0, 2, 0); stageOrd(0, 3, 0);
  VMW(4);
  SBAR;
  SCHED0;

  for (int it = 0; it < NIT; ++it) {
    int kt2 = it * 2;
    bool last = (it == NIT - 1);
#pragma unroll
    for (int p = 0; p < 8; ++p) {
      const int d = p >> 2;
      const int q = p & 3;
      const int mh = q >> 1, nh = q & 1;
      const char* Abp = (const char*)&As[d][mh][0];
      const char* Bbp = (const char*)&Bs[d][nh][0];
      if (q == 0 || q == 2) {
#pragma unroll
        for (int kk = 0; kk < 2; kk++)
#pragma unroll
          for (int i = 0; i < 4; i++) {
            int l = wr * 64 + i * 16 + rr;
            a[kk][i] = *(const short8*)(Abp + l * 128 + ((((kk << 2) + qg) ^ (rr & 7)) << 4));
          }
      }
#pragma unroll
      for (int kk = 0; kk < 2; kk++)
#pragma unroll
        for (int j = 0; j < 2; j++) {
          int l = wc * 32 + j * 16 + rr;
          b[kk][j] = *(const short8*)(Bbp + l * 128 + ((((kk << 2) + qg) ^ (rr & 7)) << 4));
        }
      if (p < 4) stageOrd(1, q, kt2 + 1);
      else if (!last) stageOrd(0, q, kt2 + 2);
      SCHED0;
      SBAR;
      LGKM0;
      SCHED0;
      __builtin_amdgcn_s_setprio(1);
#pragma unroll
      for (int kk = 0; kk < 2; kk++)
#pragma unroll
        for (int i = 0; i < 4; i++)
#pragma unroll
          for (int j = 0; j < 2; j++)
            acc[mh * 4 + i][nh * 2 + j] = __builtin_amdgcn_mfma_f32_16x16x32_bf16(
                a[kk][i], b[kk][j], acc[mh * 4 + i][nh * 2 + j], 0, 0, 0);
      __builtin_amdgcn_s_setprio(0);
      if (!last || p < 4) VMW(4);
      else if (p == 4) VMW(2);
      else if (p == 5) VMW(0);
      SBAR;
      SCHED0;
    }
  }

  int rbase = m0 + wr * 128;
  int cbase = n0 + wc * 64;
#pragma unroll
  for (int fi = 0; fi < 8; fi++) {
    int row0 = rbase + (fi >> 2) * 64 + (fi & 3) * 16 + qg * 4;
#pragma unroll
    for (int fj = 0; fj < 4; fj++) {
      int col = cbase + (fj >> 1) * 32 + (fj & 1) * 16 + rr;
      float bv = bias[col];
#pragma unroll
      for (int r = 0; r < 4; r++)
        fout[(size_t)(row0 + r) * N + col] = acc[fi][fj][r] + bv;
    }
  }
}

// ---------------- fused causal attention: 4-wave KV-split + online-softmax merge ----------------
__global__ __launch_bounds__(256) void attn_kernel(
    const u16* __restrict__ qkv, const u16* __restrict__ vt, u16* __restrict__ o) {
  __shared__ __align__(16) u16 P_s[4][16 * 48];
  __shared__ float mls[3][2][16];
  __shared__ float osm[3][16][64];
  int nwg = gridDim.x;
  int wg = xcd_swz(blockIdx.x, nwg);
  int qt = wg & 63;
  int h = (wg >> 6) % H_;
  int b = wg / (64 * H_);
  int q0 = qt << 4;
  int tid = threadIdx.x;
  int ws = tid >> 6;
  int lane = tid & 63;
  int rr = lane & 15, qg = lane >> 4, kq = qg << 3;

  const u16* qb = qkv + (size_t)(b * T_ + q0 + rr) * C3_ + h * 64;
  short8 qf0 = *(const short8*)(qb + kq);
  short8 qf1 = *(const short8*)(qb + 32 + kq);

  float m_r = -1e30f, l_r = 0.f;
  floatx4 zero = {0.f, 0.f, 0.f, 0.f};
  floatx4 oacc[4];
#pragma unroll
  for (int d = 0; d < 4; d++) oacc[d] = zero;

  const u16* kbase = qkv + (size_t)(b * T_) * C3_ + 768 + h * 64;
  const u16* vbase = vt + (size_t)(b * C_ + h * 64) * T_;

  for (int kt0 = ws * 32; kt0 <= q0 + 15; kt0 += 128) {
    floatx4 s[2];
#pragma unroll
    for (int c = 0; c < 2; c++) {
      const u16* kb = kbase + (size_t)(kt0 + c * 16 + rr) * C3_;
      short8 kf0 = *(const short8*)(kb + kq);
      short8 kf1 = *(const short8*)(kb + 32 + kq);
      floatx4 z = zero;
      z = __builtin_amdgcn_mfma_f32_16x16x32_bf16(kf0, qf0, z, 0, 0, 0);
      z = __builtin_amdgcn_mfma_f32_16x16x32_bf16(kf1, qf1, z, 0, 0, 0);
      s[c] = z;
    }
    int qpos = q0 + rr;
    float p[2][4];
    float mx = -1e30f;
#pragma unroll
    for (int c = 0; c < 2; c++)
#pragma unroll
      for (int r = 0; r < 4; r++) {
        int kpos = kt0 + c * 16 + qg * 4 + r;
        float val = s[c][r] * 0.125f;
        val = (kpos <= qpos) ? val : -1e30f;
        p[c][r] = val;
        mx = fmaxf(mx, val);
      }
    mx = fmaxf(mx, __shfl_xor(mx, 16));
    mx = fmaxf(mx, __shfl_xor(mx, 32));
    float mn = fmaxf(m_r, mx);
    float escL = exp2f((m_r - mn) * 1.44269504f);
    m_r = mn;
    float ps = 0.f;
#pragma unroll
    for (int c = 0; c < 2; c++)
#pragma unroll
      for (int r = 0; r < 4; r++) {
        float pv = exp2f((p[c][r] - mn) * 1.44269504f);
        p[c][r] = pv;
        ps += pv;
      }
    ps += __shfl_xor(ps, 16);
    ps += __shfl_xor(ps, 32);
    l_r = l_r * escL + ps;
#pragma unroll
    for (int c = 0; c < 2; c++) {
      unsigned int u0 = (unsigned int)f2bf(p[c][0]) | ((unsigned int)f2bf(p[c][1]) << 16);
      unsigned int u1 = (unsigned int)f2bf(p[c][2]) | ((unsigned int)f2bf(p[c][3]) << 16);
      uint2 pk; pk.x = u0; pk.y = u1;
      *(uint2*)&P_s[ws][rr * 48 + c * 16 + qg * 4] = pk;
    }
    float er[4];
#pragma unroll
    for (int r = 0; r < 4; r++) er[r] = __shfl(escL, qg * 4 + r);
#pragma unroll
    for (int d = 0; d < 4; d++)
#pragma unroll
      for (int r = 0; r < 4; r++) oacc[d][r] *= er[r];
    short8 pa = *(const short8*)&P_s[ws][rr * 48 + kq];
#pragma unroll
    for (int d = 0; d < 4; d++) {
      short8 vf = *(const short8*)(vbase + (size_t)(d * 16 + rr) * T_ + kt0 + kq);
      oacc[d] = __builtin_amdgcn_mfma_f32_16x16x32_bf16(pa, vf, oacc[d], 0, 0, 0);
    }
  }

  // partials -> LDS (waves 1..3); merge in wave 0
  if (ws != 0) {
    if (qg == 0) { mls[ws - 1][0][rr] = m_r; mls[ws - 1][1][rr] = l_r; }
#pragma unroll
    for (int d = 0; d < 4; d++)
#pragma unroll
      for (int r = 0; r < 4; r++)
        osm[ws - 1][qg * 4 + r][d * 16 + rr] = oacc[d][r];
  }
  __syncthreads();
  if (ws == 0) {
#pragma unroll
    for (int s2 = 0; s2 < 3; s2++) {
      float mw = mls[s2][0][rr];
      float lw = mls[s2][1][rr];
      float mn = fmaxf(m_r, mw);
      float e0 = exp2f((m_r - mn) * 1.44269504f);
      float e1 = exp2f((mw - mn) * 1.44269504f);
      m_r = mn;
      l_r = l_r * e0 + lw * e1;
      float er0[4], er1[4];
#pragma unroll
      for (int r = 0; r < 4; r++) {
        er0[r] = __shfl(e0, qg * 4 + r);
        er1[r] = __shfl(e1, qg * 4 + r);
      }
#pragma unroll
      for (int d = 0; d < 4; d++)
#pragma unroll
        for (int r = 0; r < 4; r++)
          oacc[d][r] = oacc[d][r] * er0[r] + osm[s2][qg * 4 + r][d * 16 + rr] * er1[r];
    }
    float lb[4];
#pragma unroll
    for (int r = 0; r < 4; r++) lb[r] = __shfl(l_r, qg * 4 + r);
    u16* obp = o + (size_t)(b * T_ + q0) * C_ + h * 64;
#pragma unroll
    for (int d = 0; d < 4; d++)
#pragma unroll
      for (int r = 0; r < 4; r++) {
        int row = qg * 4 + r;
        obp[(size_t)row * C_ + d * 16 + rr] = f2bf(oacc[d][r] / lb[r]);
      }
  }
}

extern "C" void kernel_launch(void* const* d_in, const int* in_sizes, int n_in,
                              void* d_out, int out_size, void* d_ws, size_t ws_size,
                              hipStream_t stream) {
  (void)in_sizes; (void)n_in; (void)out_size; (void)ws_size;
  const int*   xidx = (const int*)d_in[0];
  const float* tok  = (const float*)d_in[1];
  const float* pos  = (const float*)d_in[2];
  const float* ln1g = (const float*)d_in[3];
  const float* ln1b = (const float*)d_in[4];
  const float* wq   = (const float*)d_in[5];
  const float* wk   = (const float*)d_in[6];
  const float* wv   = (const float*)d_in[7];
  const float* wo   = (const float*)d_in[8];
  const float* bo   = (const float*)d_in[9];
  const float* ln2g = (const float*)d_in[10];
  const float* ln2b = (const float*)d_in[11];
  const float* w1   = (const float*)d_in[12];
  const float* b1   = (const float*)d_in[13];
  const float* w2   = (const float*)d_in[14];
  const float* b2   = (const float*)d_in[15];
  const float* lnfg = (const float*)d_in[16];
  const float* lnfb = (const float*)d_in[17];
  const float* wp   = (const float*)d_in[18];
  const float* bp   = (const float*)d_in[19];

  char* ws = (char*)d_ws;
  size_t off = 0;
  auto alloc = [&](size_t bytes) { char* p = ws + off; off += (bytes + 255) & ~(size_t)255; return p; };
  u16* wqkvT = (u16*)alloc((size_t)L_ * 3 * C_ * C_ * 2);   // [l][3C][C]
  u16* woT = (u16*)alloc((size_t)L_ * C_ * C_ * 2);
  u16* w1T = (u16*)alloc((size_t)L_ * C_ * F_ * 2);
  u16* w2T = (u16*)alloc((size_t)L_ * C_ * F_ * 2);
  u16* wpT = (u16*)alloc((size_t)C_ * V_ * 2);
  float* x = (float*)alloc((size_t)M_ * C_ * 4);
  float* ps0 = (float*)alloc((size_t)2 * M_ * C_ * 4);   // split-K partial slabs (kz 0/1)
  u16* hb   = (u16*)alloc((size_t)M_ * C_ * 2);
  u16* qkvb = (u16*)alloc((size_t)M_ * C3_ * 2);
  u16* vtb  = (u16*)alloc((size_t)M_ * C_ * 2);
  u16* aob  = (u16*)alloc((size_t)M_ * C_ * 2);
  u16* mb   = (u16*)alloc((size_t)M_ * F_ * 2);
  float* ps1 = ps0 + (size_t)M_ * C_;

  dim3 blk(256);
  size_t CC = (size_t)C_ * C_, CF = (size_t)C_ * F_;
  transpose4_qkvo<<<dim3(C_ / 32, C_ / 32, L_ * 4), blk, 0, stream>>>(
      wq, wk, wv, wo, wqkvT, woT);
  transpose_f32_bf16<<<dim3(F_ / 32, C_ / 32, L_), blk, 0, stream>>>(w1, w1T, C_, F_, CF, CF);
  transpose_f32_bf16<<<dim3(C_ / 32, F_ / 32, L_), blk, 0, stream>>>(w2, w2T, F_, C_, CF, CF);
  transpose_f32_bf16<<<dim3(V_ / 32, C_ / 32, 1), blk, 0, stream>>>(wp, wpT, C_, V_, 0, 0);
  embed_ln<<<M_ / 4, blk, 0, stream>>>(xidx, tok, pos, ln1g, ln1b, x, hb);

  for (int l = 0; l < L_; ++l) {
    size_t wOff = (size_t)l * 3 * CC;
    size_t oOff = (size_t)l * CC;
    size_t fOff = (size_t)l * CF;
    gemm3<256, 128, 64, 2, 2, 0, 0, 3, 1><<<dim3(M_ / 128, C3_ / 64), 256, 0, stream>>>(
        hb, wqkvT + wOff, nullptr, qkvb, nullptr, vtb, C3_, C_);
    attn_kernel<<<B_ * H_ * (T_ / 16), dim3(256), 0, stream>>>(qkvb, vtb, aob);
    gemm3<256, 128, 64, 2, 2, 1, 0, 4, 2><<<dim3(M_ / 128, C_ / 64, 2), 256, 0, stream>>>(
        aob, woT + oOff, bo + l * C_, nullptr, ps0, nullptr, C_, C_);
    ln_sum<<<M_ / 4, blk, 0, stream>>>(x, ps0, ps1, ln2g + l * C_, ln2b + l * C_, hb);
    gemm3<256, 128, 64, 2, 2, 1, 1, 0, 1><<<dim3(M_ / 128, F_ / 64), 256, 0, stream>>>(
        hb, w1T + fOff, b1 + l * F_, mb, nullptr, nullptr, F_, C_);
    gemm3<256, 128, 64, 2, 2, 1, 0, 4, 2><<<dim3(M_ / 128, C_ / 64, 2), 256, 0, stream>>>(
        mb, w2T + fOff, b2 + l * C_, nullptr, ps0, nullptr, C_, F_);
    if (l + 1 < L_)
      ln_sum<<<M_ / 4, blk, 0, stream>>>(x, ps0, ps1, ln1g + (l + 1) * C_, ln1b + (l + 1) * C_, hb);
  }
  ln_sum<<<M_ / 4, blk, 0, stream>>>(x, ps0, ps1, lnfg, lnfb, hb);
  gemm8<<<dim3(M_ / 256, V_ / 256), 512, 0, stream>>>(
      hb, wpT, bp, (float*)d_out, V_, C_);
}